// Round 9
// baseline (650.812 us; speedup 1.0000x reference)
//
#include <hip/hip_runtime.h>
#include <cstddef>

#define NB 4
#define NS 1024
#define ND 384
#define NN 16
#define MTOT 4096
#define TM 8    // rows per block (dir2_k1, ln1)
#define TMC 4   // rows per block (fallback conv, final_k)
#define NCH 32
#define CHL 32
#define NSP (NS + 2)

typedef unsigned short ushort_t;
typedef __attribute__((ext_vector_type(8))) short short8;
typedef __attribute__((ext_vector_type(4))) float f32x4;

static __device__ __forceinline__ float fget(const float4& v, int e) {
    return e == 0 ? v.x : e == 1 ? v.y : e == 2 ? v.z : v.w;
}
static __device__ __forceinline__ ushort_t f2bf(float x) {
    unsigned u = __float_as_uint(x);
    return (ushort_t)((u + 0x7FFF + ((u >> 16) & 1)) >> 16);
}
static __device__ __forceinline__ float bf2f(ushort_t h) {
    return __uint_as_float(((unsigned)h) << 16);
}

// ---------------- weight packing ----------------
// [0,2654208)            : Wp bf16 [nblk(12)][ks(108)][nr(64)][kc(32)]
// [2654208,3538944)      : wp1P, wp2P f32 float4-packed conv3 (fallback)
// [3538944,3981312)      : wp3P, wcfP, wcbP
// [3981312,4024320)      : wdbc1P, wdbc2P
// [4024320,4042752)      : wdt1T, wdt2T
__global__ __launch_bounds__(256) void prep_weights(
    const float* __restrict__ w_p1, const float* __restrict__ w_p2,
    const float* __restrict__ w_p3, const float* __restrict__ w_cf,
    const float* __restrict__ w_cb,
    const float* __restrict__ w_dbc1, const float* __restrict__ w_dbc2,
    const float* __restrict__ w_dt1,  const float* __restrict__ w_dt2,
    ushort_t* __restrict__ Wp,
    float* __restrict__ wp1P, float* __restrict__ wp2P,
    float* __restrict__ wp3P, float* __restrict__ wcfP, float* __restrict__ wcbP,
    float* __restrict__ wdbc1P, float* __restrict__ wdbc2P,
    float* __restrict__ wdt1T,  float* __restrict__ wdt2T)
{
    int idx = blockIdx.x * 256 + threadIdx.x;
    if (idx < 2654208) {                      // Wp bf16 (hi/lo segments)
        int kc = idx & 31; int nr = (idx >> 5) & 63; int chunk = idx >> 11;
        int ks = chunk % 108; int nblk = chunk / 108;
        int n = nblk * 64 + nr;
        int keff = ks * 32 + kc;
        int seg = keff / 1152; int r = keff - seg * 1152;
        int k3 = r / 384; int i = r - k3 * 384;
        const float* mat = (n < 384) ? w_p2 : w_p1;
        float v = mat[((size_t)(n & 383) * 384 + i) * 3 + k3];
        ushort_t hi = f2bf(v);
        ushort_t outv = hi;
        if (seg == 1) outv = f2bf(v - bf2f(hi));
        Wp[idx] = outv;
    } else if (idx < 3538944) {               // wp1P, wp2P f32 (fallback conv)
        int q = idx - 2654208; const float* w; float* wT;
        if (q < 442368) { w = w_p1; wT = wp1P; }
        else            { q -= 442368; w = w_p2; wT = wp2P; }
        int e = q & 3; int o = (q >> 2) % 384; int kk = q / 1536;
        int k = kk / 96; int i = (kk % 96) * 4 + e;
        wT[q] = w[((size_t)o * 384 + i) * 3 + k];
    } else if (idx < 3981312) {               // wp3P, wcfP, wcbP (384x384)
        int q = idx - 3538944; const float* w; float* wT;
        if (q < 147456)      { w = w_p3; wT = wp3P; }
        else if (q < 294912) { q -= 147456; w = w_cf; wT = wcfP; }
        else                 { q -= 294912; w = w_cb; wT = wcbP; }
        int e = q & 3; int o = (q >> 2) % 384; int i = (q / 1536) * 4 + e;
        wT[q] = w[(size_t)o * 384 + i];
    } else if (idx < 4024320) {               // wdbc1P, wdbc2P (56x384)
        int q = idx - 3981312; const float* w; float* wT;
        if (q < 21504) { w = w_dbc1; wT = wdbc1P; }
        else           { q -= 21504; w = w_dbc2; wT = wdbc2P; }
        int e = q & 3; int oc = (q >> 2) % 56; int i = (q / 224) * 4 + e;
        wT[q] = w[(size_t)oc * 384 + i];
    } else if (idx < 4042752) {               // wdt1T, wdt2T
        int q = idx - 4024320; const float* w; float* wT;
        if (q < 9216) { w = w_dt1; wT = wdt1T; }
        else          { q -= 9216; w = w_dt2; wT = wdt2T; }
        int d = q % 384; int qq = q / 384;
        wT[q] = w[(size_t)d * 24 + qq];
    }
}

// ---------------- LN1 -> f32 XNPf + bf16 splits XH/XL, all padded ----------------
__global__ __launch_bounds__(384) void ln1_k(
    const float* __restrict__ x,
    const float* __restrict__ g_n, const float* __restrict__ bt_n,
    float* __restrict__ XNPf, ushort_t* __restrict__ XH, ushort_t* __restrict__ XL)
{
    int blk = blockIdx.x;
    int t = threadIdx.x, wid = t >> 6, lane = t & 63;
    if (blk == MTOT / TM) {                   // guard rows = 0
        for (int b = 0; b < NB; ++b) {
            size_t o0 = ((size_t)b * NSP + 0) * ND + t;
            size_t o1 = ((size_t)b * NSP + NS + 1) * ND + t;
            XNPf[o0] = 0.f; XNPf[o1] = 0.f;
            XH[o0] = 0; XL[o0] = 0; XH[o1] = 0; XL[o1] = 0;
        }
        return;
    }
    int m0 = blk * TM;
    int b = m0 >> 10, s0 = m0 & 1023;
    for (int j = wid; j < TM; j += 6) {
        int r = s0 + j;
        const float* row = x + ((size_t)(b * NS + r)) * ND;
        float v[6]; float s1 = 0.f, s2 = 0.f;
        #pragma unroll
        for (int e = 0; e < 6; ++e) {
            v[e] = row[lane + 64 * e];
            s1 += v[e]; s2 += v[e] * v[e];
        }
        #pragma unroll
        for (int o = 32; o; o >>= 1) {
            s1 += __shfl_xor(s1, o);
            s2 += __shfl_xor(s2, o);
        }
        float mu = s1 * (1.f / ND);
        float var = s2 * (1.f / ND) - mu * mu;
        float rs = rsqrtf(var + 1e-5f);
        size_t ob = ((size_t)b * NSP + r + 1) * ND;
        #pragma unroll
        for (int e = 0; e < 6; ++e) {
            int i = lane + 64 * e;
            float val = (v[e] - mu) * rs * g_n[i] + bt_n[i];
            XNPf[ob + i] = val;
            ushort_t hi = f2bf(val);
            XH[ob + i] = hi;
            XL[ob + i] = f2bf(val - bf2f(hi));
        }
    }
}

// ---------------- conv3 x2 as split-bf16 MFMA GEMM (experimental path) ----------------
__global__ __launch_bounds__(256) void conv_mfma(
    const ushort_t* __restrict__ XH, const ushort_t* __restrict__ XL,
    const ushort_t* __restrict__ Wp,
    const float* __restrict__ b_p2, const float* __restrict__ b_p1,
    float* __restrict__ XP, float* __restrict__ Z1)
{
    __shared__ ushort_t lds_a[64][40];
    __shared__ ushort_t lds_b[64][40];
    int blk = blockIdx.x;
    int mtile = blk & 63, ntile = blk >> 6;
    int m0 = mtile * 64;
    int b = m0 >> 10, s0 = m0 & 1023;
    int n0 = ntile * 64;
    int t = threadIdx.x;
    int lane = t & 63, w = t >> 6;
    int wr = w >> 1, wc = w & 1;
    int srow = t >> 2;
    int schunk = (t & 3) * 8;

    f32x4 acc[2][2] = {};

    for (int ks = 0; ks < 108; ++ks) {
        int seg = ks / 36;
        int rem = ks - seg * 36;
        int k3 = rem / 12;
        int i0 = (rem - k3 * 12) * 32;
        const ushort_t* XS = (ks < 72) ? XH : XL;
        uint4 av = *reinterpret_cast<const uint4*>(
            XS + ((size_t)(b * NSP + s0 + srow + k3) * ND + i0 + schunk));
        uint4 bv = *reinterpret_cast<const uint4*>(
            Wp + ((size_t)(ntile * 108 + ks) * 2048 + t * 8));
        __syncthreads();
        *reinterpret_cast<uint4*>(&lds_a[srow][schunk]) = av;
        *reinterpret_cast<uint4*>(&lds_b[srow][schunk]) = bv;
        __syncthreads();
        short8 af[2], bf[2];
        #pragma unroll
        for (int mi = 0; mi < 2; ++mi)
            af[mi] = *reinterpret_cast<const short8*>(
                &lds_a[wr * 32 + mi * 16 + (lane & 15)][(lane >> 4) * 8]);
        #pragma unroll
        for (int ni = 0; ni < 2; ++ni)
            bf[ni] = *reinterpret_cast<const short8*>(
                &lds_b[wc * 32 + ni * 16 + (lane & 15)][(lane >> 4) * 8]);
        #pragma unroll
        for (int mi = 0; mi < 2; ++mi)
            #pragma unroll
            for (int ni = 0; ni < 2; ++ni)
                acc[mi][ni] = __builtin_amdgcn_mfma_f32_16x16x32_bf16(
                    af[mi], bf[ni], acc[mi][ni], 0, 0, 0);
    }

    #pragma unroll
    for (int mi = 0; mi < 2; ++mi) {
        #pragma unroll
        for (int ni = 0; ni < 2; ++ni) {
            int n = n0 + wc * 32 + ni * 16 + (lane & 15);
            #pragma unroll
            for (int j = 0; j < 4; ++j) {
                int m = m0 + wr * 32 + mi * 16 + (lane >> 4) * 4 + j;
                float v = acc[mi][ni][j];
                if (n < 384) XP[(size_t)m * ND + n] = v + b_p2[n];
                else         Z1[(size_t)m * ND + (n - 384)] = v + b_p1[n - 384];
            }
        }
    }
}

// ---------------- verify: sample-check MFMA conv vs f32 recompute ----------------
// 4096 samples: every m (bijective 37*gid mod 4096), all n covered (149*gid mod 768)
__global__ __launch_bounds__(256) void verify_k(
    const float* __restrict__ XNPf,
    const float* __restrict__ w_p2, const float* __restrict__ b_p2,
    const float* __restrict__ w_p1, const float* __restrict__ b_p1,
    const float* __restrict__ XP, const float* __restrict__ Z1,
    int* __restrict__ flag)
{
    int gid = blockIdx.x * 256 + threadIdx.x;   // 16 blocks -> 4096 samples
    int m = (gid * 37) & 4095;
    int n = (gid * 149) % 768;
    int b = m >> 10, s = m & 1023;
    const float* w = (n < 384) ? w_p2 : w_p1;
    int o = n & 383;
    float a = (n < 384) ? b_p2[o] : b_p1[o];
    for (int k3 = 0; k3 < 3; ++k3) {
        const float* xr = XNPf + ((size_t)(b * NSP + s + k3)) * ND;
        const float* wr = w + (size_t)o * 1152 + k3;
        for (int i = 0; i < 384; ++i) a = fmaf(xr[i], wr[i * 3], a);
    }
    float got = (n < 384) ? XP[(size_t)m * ND + o] : Z1[(size_t)m * ND + o];
    if (fabsf(got - a) > 0.05f) atomicOr(flag, 1);
}

// ---------------- fallback conv (round-7 verified f32 path), gated on flag ----------
__global__ __launch_bounds__(384) void conv_fb(
    const int* __restrict__ flag,
    const float* __restrict__ XNP,
    const float* __restrict__ wp2P, const float* __restrict__ b_p2,
    const float* __restrict__ wp1P, const float* __restrict__ b_p1,
    float* __restrict__ XP, float* __restrict__ Z1)
{
    if (((const volatile int*)flag)[0] == 0) return;   // MFMA verified OK
    int m0 = blockIdx.x * TMC;
    int b = m0 >> 10, s0 = m0 & 1023;
    int t = threadIdx.x;
    const float4* xnp4 = reinterpret_cast<const float4*>(XNP);
    const float4* w2f4 = reinterpret_cast<const float4*>(wp2P) + t;
    const float4* w1f4 = reinterpret_cast<const float4*>(wp1P) + t;

    float a2[TMC], a1[TMC];
    #pragma unroll
    for (int r = 0; r < TMC; ++r) { a2[r] = b_p2[t]; a1[r] = b_p1[t]; }

    size_t base = (size_t)(b * NSP + s0) * 96;
    float4 W2c = w2f4[0], W1c = w1f4[0];
    float4 xc[TMC];
    #pragma unroll
    for (int r = 0; r < TMC; ++r) xc[r] = xnp4[base + (size_t)r * 96];

    for (int kk = 0; kk < 288; ++kk) {
        int kn = (kk < 287) ? kk + 1 : 287;
        float4 W2n = w2f4[(size_t)kn * 384];
        float4 W1n = w1f4[(size_t)kn * 384];
        int k_n = kn / 96, i4_n = kn - k_n * 96;
        size_t rbn = base + (size_t)k_n * 96 + i4_n;
        float4 xn_[TMC];
        #pragma unroll
        for (int r = 0; r < TMC; ++r) xn_[r] = xnp4[rbn + (size_t)r * 96];
        #pragma unroll
        for (int e = 0; e < 4; ++e) {
            float wv2 = fget(W2c, e);
            float wv1 = fget(W1c, e);
            #pragma unroll
            for (int r = 0; r < TMC; ++r) {
                float xe = fget(xc[r], e);
                a2[r] = fmaf(xe, wv2, a2[r]);
                a1[r] = fmaf(xe, wv1, a1[r]);
            }
        }
        W2c = W2n; W1c = W1n;
        #pragma unroll
        for (int r = 0; r < TMC; ++r) xc[r] = xn_[r];
    }
    #pragma unroll
    for (int r = 0; r < TMC; ++r) {
        size_t ix = (size_t)(m0 + r) * ND + t;
        XP[ix] = a2[r];
        Z1[ix] = a1[r];
    }
}

// ---------------- both directions: K=1 conv + LN2 + dbc + delta ----------------
__global__ __launch_bounds__(384) void dir2_k1(
    const float* __restrict__ XP,
    const float* __restrict__ wcfP, const float* __restrict__ b_cf,
    const float* __restrict__ g_nf, const float* __restrict__ bt_nf,
    const float* __restrict__ wdbc1P, const float* __restrict__ wdt1T,
    const float* __restrict__ b_dt1,
    const float* __restrict__ wcbP, const float* __restrict__ b_cb,
    const float* __restrict__ g_nb, const float* __restrict__ bt_nb,
    const float* __restrict__ wdbc2P, const float* __restrict__ wdt2T,
    const float* __restrict__ b_dt2,
    float* __restrict__ LN2, float* __restrict__ DBC2, float* __restrict__ DEL2)
{
    __shared__ float uo[TM][ND];
    __shared__ float red[TM][6][2];
    __shared__ float dbcS[TM][56];
    int blk = blockIdx.x;
    int dir = blk >> 9;
    int m0 = (blk & 511) * TM;
    int b = m0 >> 10, s0 = m0 & 1023;
    int t = threadIdx.x, wid = t >> 6, lane = t & 63;

    const float* wcP   = dir ? wcbP   : wcfP;
    const float* b_c   = dir ? b_cb   : b_cf;
    const float* g     = dir ? g_nb   : g_nf;
    const float* bt    = dir ? bt_nb  : bt_nf;
    const float* wdbcP = dir ? wdbc2P : wdbc1P;
    const float* wdtT  = dir ? wdt2T  : wdt1T;
    const float* b_dt  = dir ? b_dt2  : b_dt1;
    const size_t NM = (size_t)MTOT * ND;
    float* LNo  = LN2  + (size_t)dir * NM;
    float* DBCo = DBC2 + (size_t)dir * MTOT * 56;
    float* DELo = DEL2 + (size_t)dir * NM;

    const float4* XPf4 = reinterpret_cast<const float4*>(XP);
    size_t rowb[TM];
    #pragma unroll
    for (int r = 0; r < TM; ++r) {
        int s = s0 + r;
        int sE = dir ? (NS - 1 - s) : s;
        rowb[r] = ((size_t)(b * NS + sE)) * 96;
    }

    const float4* wcf4 = reinterpret_cast<const float4*>(wcP) + t;
    float acc[TM];
    #pragma unroll
    for (int r = 0; r < TM; ++r) acc[r] = b_c[t];
    float4 Wc = wcf4[0];
    float4 xc[TM];
    #pragma unroll
    for (int r = 0; r < TM; ++r) xc[r] = XPf4[rowb[r]];
    for (int i4 = 0; i4 < 96; ++i4) {
        int in_ = (i4 < 95) ? i4 + 1 : 95;
        float4 Wn = wcf4[(size_t)in_ * 384];
        float4 xn_[TM];
        #pragma unroll
        for (int r = 0; r < TM; ++r) xn_[r] = XPf4[rowb[r] + in_];
        #pragma unroll
        for (int e = 0; e < 4; ++e) {
            float wv = fget(Wc, e);
            #pragma unroll
            for (int r = 0; r < TM; ++r)
                acc[r] = fmaf(fget(xc[r], e), wv, acc[r]);
        }
        Wc = Wn;
        #pragma unroll
        for (int r = 0; r < TM; ++r) xc[r] = xn_[r];
    }

    #pragma unroll
    for (int r = 0; r < TM; ++r) {
        float s1 = acc[r], s2 = acc[r] * acc[r];
        #pragma unroll
        for (int o = 32; o; o >>= 1) {
            s1 += __shfl_xor(s1, o);
            s2 += __shfl_xor(s2, o);
        }
        if (lane == 0) { red[r][wid][0] = s1; red[r][wid][1] = s2; }
    }
    __syncthreads();
    float gt = g[t], btt = bt[t];
    #pragma unroll
    for (int r = 0; r < TM; ++r) {
        float s1 = 0.f, s2 = 0.f;
        #pragma unroll
        for (int w = 0; w < 6; ++w) { s1 += red[r][w][0]; s2 += red[r][w][1]; }
        float mu = s1 * (1.f / ND);
        float var = s2 * (1.f / ND) - mu * mu;
        float rs = rsqrtf(var + 1e-5f);
        float ln = (acc[r] - mu) * rs * gt + btt;
        uo[r][t] = ln;
        LNo[(size_t)(m0 + r) * ND + t] = ln;
    }
    __syncthreads();

    for (int r = wid; r < TM; r += 6) {
        if (lane < 56) {
            const float4* wdf4 = reinterpret_cast<const float4*>(wdbcP) + lane;
            const float4* uof4 = reinterpret_cast<const float4*>(&uo[r][0]);
            float a = 0.f;
            float4 Wd = wdf4[0];
            for (int i4 = 0; i4 < 96; ++i4) {
                int in_ = (i4 < 95) ? i4 + 1 : 95;
                float4 Wdn = wdf4[(size_t)in_ * 56];
                float4 uv = uof4[i4];
                a = fmaf(uv.x, Wd.x, a);
                a = fmaf(uv.y, Wd.y, a);
                a = fmaf(uv.z, Wd.z, a);
                a = fmaf(uv.w, Wd.w, a);
                Wd = Wdn;
            }
            dbcS[r][lane] = a;
            DBCo[(size_t)(m0 + r) * 56 + lane] = a;
        }
    }
    __syncthreads();

    float accD[TM]; float bd = b_dt[t];
    #pragma unroll
    for (int r = 0; r < TM; ++r) accD[r] = bd;
    for (int q = 0; q < 24; ++q) {
        float wv = wdtT[q * 384 + t];
        #pragma unroll
        for (int r = 0; r < TM; ++r) accD[r] = fmaf(dbcS[r][q], wv, accD[r]);
    }
    #pragma unroll
    for (int r = 0; r < TM; ++r) {
        float a = accD[r];
        DELo[(size_t)(m0 + r) * ND + t] =
            fmaxf(a, 0.f) + log1pf(__expf(-fabsf(a)));
    }
}

// ---------------- parallel scan ----------------
__global__ __launch_bounds__(384) void scan_s1(
    const float* __restrict__ DEL2, const float* __restrict__ LN2,
    const float* __restrict__ DBC2, const float* __restrict__ A_log1,
    const float* __restrict__ A_log2,
    float* __restrict__ P, float* __restrict__ H)
{
    __shared__ float bc[CHL][32];
    int blk = blockIdx.x;
    int c = blk & (NCH - 1);
    int db = blk >> 5;
    int dir = db >> 2, b = db & 3;
    int t = threadIdx.x;
    const float* del  = DEL2 + (size_t)dir * MTOT * ND;
    const float* u    = LN2  + (size_t)dir * MTOT * ND;
    const float* dbc  = DBC2 + (size_t)dir * MTOT * 56;
    const float* Alog = dir ? A_log2 : A_log1;

    for (int e = t; e < CHL * 32; e += 384) {
        int row = e >> 5, col = e & 31;
        bc[row][col] = dbc[((size_t)(b * NS + c * CHL + row)) * 56 + 24 + col];
    }
    __syncthreads();

    float A[NN], h[NN], p[NN];
    #pragma unroll
    for (int n = 0; n < NN; ++n) {
        A[n] = -__expf(Alog[(size_t)t * NN + n]);
        h[n] = 0.f; p[n] = 1.f;
    }
    for (int j = 0; j < CHL; ++j) {
        size_t rix = (size_t)b * NS + c * CHL + j;
        float dl = del[rix * ND + t];
        float uv = u[rix * ND + t];
        float dx = dl * uv;
        #pragma unroll
        for (int n = 0; n < NN; ++n) {
            float da = __expf(dl * A[n]);
            h[n] = fmaf(da, h[n], dx * bc[j][n]);
            p[n] *= da;
        }
    }
    size_t base = ((size_t)blk * ND + t) * NN;
    #pragma unroll
    for (int n = 0; n < NN; ++n) { P[base + n] = p[n]; H[base + n] = h[n]; }
}

__global__ __launch_bounds__(256) void scan_s2(
    float* __restrict__ P, const float* __restrict__ H)
{
    int gid = blockIdx.x * 256 + threadIdx.x;
    int n = gid & 15;
    int d = (gid >> 4) % ND;
    int db = gid / (16 * ND);
    float h = 0.f;
    for (int c = 0; c < NCH; ++c) {
        size_t idx = (((size_t)db * NCH + c) * ND + d) * NN + n;
        float p = P[idx];
        float hh = H[idx];
        P[idx] = h;
        h = fmaf(p, h, hh);
    }
}

__global__ __launch_bounds__(384) void scan_s3(
    const float* __restrict__ DEL2, const float* __restrict__ LN2,
    const float* __restrict__ DBC2, const float* __restrict__ A_log1,
    const float* __restrict__ A_log2, const float* __restrict__ D1,
    const float* __restrict__ D2, const float* __restrict__ Hinit,
    float* __restrict__ Y2)
{
    __shared__ float bc[CHL][32];
    int blk = blockIdx.x;
    int c = blk & (NCH - 1);
    int db = blk >> 5;
    int dir = db >> 2, b = db & 3;
    int t = threadIdx.x;
    const float* del  = DEL2 + (size_t)dir * MTOT * ND;
    const float* u    = LN2  + (size_t)dir * MTOT * ND;
    const float* dbc  = DBC2 + (size_t)dir * MTOT * 56;
    const float* Alog = dir ? A_log2 : A_log1;
    const float* Dv   = dir ? D2 : D1;
    float* y          = Y2 + (size_t)dir * MTOT * ND;

    for (int e = t; e < CHL * 32; e += 384) {
        int row = e >> 5, col = e & 31;
        bc[row][col] = dbc[((size_t)(b * NS + c * CHL + row)) * 56 + 24 + col];
    }
    __syncthreads();

    size_t base = ((size_t)blk * ND + t) * NN;
    float A[NN], h[NN];
    #pragma unroll
    for (int n = 0; n < NN; ++n) {
        A[n] = -__expf(Alog[(size_t)t * NN + n]);
        h[n] = Hinit[base + n];
    }
    float Dd = Dv[t];
    for (int j = 0; j < CHL; ++j) {
        size_t rix = (size_t)b * NS + c * CHL + j;
        float dl = del[rix * ND + t];
        float uv = u[rix * ND + t];
        float dx = dl * uv;
        float y0 = 0.f, y1 = 0.f;
        #pragma unroll
        for (int n = 0; n < NN; n += 2) {
            float da0 = __expf(dl * A[n]);
            float da1 = __expf(dl * A[n + 1]);
            h[n]     = fmaf(da0, h[n],     dx * bc[j][n]);
            h[n + 1] = fmaf(da1, h[n + 1], dx * bc[j][n + 1]);
            y0 = fmaf(h[n],     bc[j][16 + n],     y0);
            y1 = fmaf(h[n + 1], bc[j][16 + n + 1], y1);
        }
        y[rix * ND + t] = y0 + y1 + Dd * uv;
    }
}

// ---------------- gate: X3 = (YF+YB) * silu(Z1) ----------------
__global__ __launch_bounds__(256) void gate_k(
    const float* __restrict__ Z1, const float* __restrict__ YF,
    const float* __restrict__ YB, float* __restrict__ X3)
{
    int i = blockIdx.x * 256 + threadIdx.x;
    const float4* z4 = reinterpret_cast<const float4*>(Z1);
    const float4* f4 = reinterpret_cast<const float4*>(YF);
    const float4* b4 = reinterpret_cast<const float4*>(YB);
    float4* o4 = reinterpret_cast<float4*>(X3);
    float4 z = z4[i], f = f4[i], bb = b4[i], o;
    o.x = (f.x + bb.x) * (z.x / (1.f + __expf(-z.x)));
    o.y = (f.y + bb.y) * (z.y / (1.f + __expf(-z.y)));
    o.z = (f.z + bb.z) * (z.z / (1.f + __expf(-z.z)));
    o.w = (f.w + bb.w) * (z.w / (1.f + __expf(-z.w)));
    o4[i] = o;
}

// ---------------- final projection + skip ----------------
__global__ __launch_bounds__(384) void final_k(
    const float* __restrict__ x, const float* __restrict__ X3,
    const float* __restrict__ wp3P, const float* __restrict__ b_p3,
    float* __restrict__ out)
{
    int m0 = blockIdx.x * TMC;
    int t = threadIdx.x;
    const float4* x3f4 = reinterpret_cast<const float4*>(X3);
    const float4* wpf4 = reinterpret_cast<const float4*>(wp3P) + t;
    size_t rb = (size_t)m0 * 96;

    float acc[TMC]; float bp = b_p3[t];
    #pragma unroll
    for (int r = 0; r < TMC; ++r) acc[r] = bp;
    float4 Wp = wpf4[0];
    float4 xc[TMC];
    #pragma unroll
    for (int r = 0; r < TMC; ++r) xc[r] = x3f4[rb + (size_t)r * 96];
    for (int i4 = 0; i4 < 96; ++i4) {
        int in_ = (i4 < 95) ? i4 + 1 : 95;
        float4 Wn = wpf4[(size_t)in_ * 384];
        float4 xn_[TMC];
        #pragma unroll
        for (int r = 0; r < TMC; ++r) xn_[r] = x3f4[rb + (size_t)r * 96 + in_];
        #pragma unroll
        for (int e = 0; e < 4; ++e) {
            float wv = fget(Wp, e);
            #pragma unroll
            for (int r = 0; r < TMC; ++r)
                acc[r] = fmaf(fget(xc[r], e), wv, acc[r]);
        }
        Wp = Wn;
        #pragma unroll
        for (int r = 0; r < TMC; ++r) xc[r] = xn_[r];
    }
    #pragma unroll
    for (int r = 0; r < TMC; ++r) {
        size_t ix = (size_t)(m0 + r) * ND + t;
        out[ix] = acc[r] + x[ix];
    }
}

__global__ __launch_bounds__(256) void fill_f32(float* out, float v, int n)
{
    int i = blockIdx.x * 256 + threadIdx.x;
    if (i < n) out[i] = v;
}

// ---------------- launch ----------------
extern "C" void kernel_launch(void* const* d_in, const int* in_sizes, int n_in,
                              void* d_out, int out_size, void* d_ws, size_t ws_size,
                              hipStream_t stream) {
    float* out = (float*)d_out;

    if (out_size != MTOT * ND) {
        fill_f32<<<(out_size + 255) / 256, 256, 0, stream>>>(
            out, 70000.f + (float)(out_size >> 16), out_size);
        return;
    }

    const float* x      = (const float*)d_in[0];
    const float* w_p1   = (const float*)d_in[1];
    const float* b_p1   = (const float*)d_in[2];
    const float* w_p2   = (const float*)d_in[3];
    const float* b_p2   = (const float*)d_in[4];
    const float* w_p3   = (const float*)d_in[5];
    const float* b_p3   = (const float*)d_in[6];
    const float* w_cf   = (const float*)d_in[7];
    const float* b_cf   = (const float*)d_in[8];
    const float* w_cb   = (const float*)d_in[9];
    const float* b_cb   = (const float*)d_in[10];
    const float* g_n    = (const float*)d_in[11];
    const float* bt_n   = (const float*)d_in[12];
    const float* g_nf   = (const float*)d_in[13];
    const float* bt_nf  = (const float*)d_in[14];
    const float* g_nb   = (const float*)d_in[15];
    const float* bt_nb  = (const float*)d_in[16];
    const float* w_dbc1 = (const float*)d_in[17];
    const float* w_dt1  = (const float*)d_in[18];
    const float* b_dt1  = (const float*)d_in[19];
    const float* A_log1 = (const float*)d_in[20];
    const float* D1     = (const float*)d_in[21];
    const float* w_dbc2 = (const float*)d_in[22];
    const float* w_dt2  = (const float*)d_in[23];
    const float* b_dt2  = (const float*)d_in[24];
    const float* A_log2 = (const float*)d_in[25];
    const float* D2     = (const float*)d_in[26];

    const size_t NM = (size_t)MTOT * ND;
    const size_t N56 = (size_t)MTOT * 56;
    const size_t AGG = (size_t)2 * NB * NCH * ND * NN;
    size_t off = 0;
    float* ws = (float*)d_ws;
    float* XP    = ws + off; off += NM;
    float* Z1    = ws + off; off += NM;
    float* LN2   = ws + off; off += 2 * NM;
    float* DEL2  = ws + off; off += 2 * NM;
    float* Y2    = ws + off; off += 2 * NM;
    float* DBC2  = ws + off; off += 2 * N56;
    float* wp1P   = ws + off; off += 442368;
    float* wp2P   = ws + off; off += 442368;
    float* wp3P   = ws + off; off += 147456;
    float* wcfP   = ws + off; off += 147456;
    float* wcbP   = ws + off; off += 147456;
    float* wdbc1P = ws + off; off += 21504;
    float* wdbc2P = ws + off; off += 21504;
    float* wdt1T  = ws + off; off += 9216;
    float* wdt2T  = ws + off; off += 9216;
    float* Pagg  = ws + off; off += AGG;
    float* Hagg  = ws + off; off += AGG;
    const size_t ws_need = off;

    if (ws_size < ws_need * sizeof(float)) {
        fill_f32<<<(out_size + 255) / 256, 256, 0, stream>>>(out, 60000.f, out_size);
        return;
    }

    float* YF   = Y2;         float* YB   = Y2 + NM;
    // aliases (stream-ordered, lifetimes disjoint):
    // XH/XL (bf16) in Y2 until conv done (scan_s3 writes Y2 later).
    // XNPf (f32 padded LN1) in DEL2 until conv_fb done (dir2 writes DEL2 later).
    // Wp (bf16 weights) in Hagg until conv done (scan_s1 writes H later).
    // flag in Pagg[0] until conv_fb done (scan_s1 writes P later).
    // X3 in DEL2 after scan_s3 consumed DEL2.
    ushort_t* XH = (ushort_t*)Y2;
    ushort_t* XL = XH + (size_t)NB * NSP * ND;
    float* XNPf = DEL2;
    ushort_t* Wp = (ushort_t*)Hagg;
    int* flag = (int*)Pagg;
    float* X3  = DEL2;

    prep_weights<<<15792, 256, 0, stream>>>(
        w_p1, w_p2, w_p3, w_cf, w_cb, w_dbc1, w_dbc2, w_dt1, w_dt2,
        Wp, wp1P, wp2P, wp3P, wcfP, wcbP, wdbc1P, wdbc2P, wdt1T, wdt2T);

    fill_f32<<<1, 256, 0, stream>>>((float*)flag, 0.f, 1);

    ln1_k<<<MTOT / TM + 1, 384, 0, stream>>>(x, g_n, bt_n, XNPf, XH, XL);

    conv_mfma<<<64 * 12, 256, 0, stream>>>(XH, XL, Wp, b_p2, b_p1, XP, Z1);

    verify_k<<<16, 256, 0, stream>>>(XNPf, w_p2, b_p2, w_p1, b_p1, XP, Z1, flag);

    conv_fb<<<MTOT / TMC, 384, 0, stream>>>(
        flag, XNPf, wp2P, b_p2, wp1P, b_p1, XP, Z1);

    dir2_k1<<<2 * (MTOT / TM), 384, 0, stream>>>(
        XP,
        wcfP, b_cf, g_nf, bt_nf, wdbc1P, wdt1T, b_dt1,
        wcbP, b_cb, g_nb, bt_nb, wdbc2P, wdt2T, b_dt2,
        LN2, DBC2, DEL2);

    scan_s1<<<2 * NB * NCH, 384, 0, stream>>>(
        DEL2, LN2, DBC2, A_log1, A_log2, Pagg, Hagg);
    scan_s2<<<(2 * NB * ND * NN) / 256, 256, 0, stream>>>(Pagg, Hagg);
    scan_s3<<<2 * NB * NCH, 384, 0, stream>>>(
        DEL2, LN2, DBC2, A_log1, A_log2, D1, D2, Pagg, Y2);

    gate_k<<<(int)(NM / 4 / 256), 256, 0, stream>>>(Z1, YF, YB, X3);

    final_k<<<MTOT / TMC, 384, 0, stream>>>(
        x, X3, wp3P, b_p3, out);
}

// Round 10
// 632.418 us; speedup vs baseline: 1.0291x; 1.0291x over previous
//
#include <hip/hip_runtime.h>
#include <cstddef>

#define NB 4
#define NS 1024
#define ND 384
#define NN 16
#define MTOT 4096
#define TM 8    // rows per block (dir2_k1, ln1)
#define TMC 4   // rows per block (fallback conv, final_k)
#define NCH 32
#define CHL 32
#define NSP (NS + 2)

typedef unsigned short ushort_t;
typedef __attribute__((ext_vector_type(8))) short short8;
typedef __attribute__((ext_vector_type(4))) short short4v;
typedef __attribute__((ext_vector_type(4))) float f32x4;

static __device__ __forceinline__ float fget(const float4& v, int e) {
    return e == 0 ? v.x : e == 1 ? v.y : e == 2 ? v.z : v.w;
}
static __device__ __forceinline__ ushort_t f2bf(float x) {
    unsigned u = __float_as_uint(x);
    return (ushort_t)((u + 0x7FFF + ((u >> 16) & 1)) >> 16);
}
static __device__ __forceinline__ float bf2f(ushort_t h) {
    return __uint_as_float(((unsigned)h) << 16);
}

// fragment gather: two K=16 halves (tr-read-derived layout, m156/m162).
// elems 0-3 <- k = kg..kg+3 (low half unless SWAP), elems 4-7 <- +16.
static __device__ __forceinline__ short8 fld(const ushort_t* rowp, int kg, int swap) {
    const short4v* p0 = reinterpret_cast<const short4v*>(rowp + (swap ? 16 : 0) + kg);
    const short4v* p1 = reinterpret_cast<const short4v*>(rowp + (swap ? 0 : 16) + kg);
    return __builtin_shufflevector(*p0, *p1, 0, 1, 2, 3, 4, 5, 6, 7);
}

// ---------------- weight packing ----------------
__global__ __launch_bounds__(256) void prep_weights(
    const float* __restrict__ w_p1, const float* __restrict__ w_p2,
    const float* __restrict__ w_p3, const float* __restrict__ w_cf,
    const float* __restrict__ w_cb,
    const float* __restrict__ w_dbc1, const float* __restrict__ w_dbc2,
    const float* __restrict__ w_dt1,  const float* __restrict__ w_dt2,
    ushort_t* __restrict__ Wp,
    float* __restrict__ wp1P, float* __restrict__ wp2P,
    float* __restrict__ wp3P, float* __restrict__ wcfP, float* __restrict__ wcbP,
    float* __restrict__ wdbc1P, float* __restrict__ wdbc2P,
    float* __restrict__ wdt1T,  float* __restrict__ wdt2T)
{
    int idx = blockIdx.x * 256 + threadIdx.x;
    if (idx < 2654208) {                      // Wp bf16 (hi/lo segments)
        int kc = idx & 31; int nr = (idx >> 5) & 63; int chunk = idx >> 11;
        int ks = chunk % 108; int nblk = chunk / 108;
        int n = nblk * 64 + nr;
        int keff = ks * 32 + kc;
        int seg = keff / 1152; int r = keff - seg * 1152;
        int k3 = r / 384; int i = r - k3 * 384;
        const float* mat = (n < 384) ? w_p2 : w_p1;
        float v = mat[((size_t)(n & 383) * 384 + i) * 3 + k3];
        ushort_t hi = f2bf(v);
        ushort_t outv = hi;
        if (seg == 1) outv = f2bf(v - bf2f(hi));
        Wp[idx] = outv;
    } else if (idx < 3538944) {               // wp1P, wp2P f32 (fallback conv)
        int q = idx - 2654208; const float* w; float* wT;
        if (q < 442368) { w = w_p1; wT = wp1P; }
        else            { q -= 442368; w = w_p2; wT = wp2P; }
        int e = q & 3; int o = (q >> 2) % 384; int kk = q / 1536;
        int k = kk / 96; int i = (kk % 96) * 4 + e;
        wT[q] = w[((size_t)o * 384 + i) * 3 + k];
    } else if (idx < 3981312) {               // wp3P, wcfP, wcbP (384x384)
        int q = idx - 3538944; const float* w; float* wT;
        if (q < 147456)      { w = w_p3; wT = wp3P; }
        else if (q < 294912) { q -= 147456; w = w_cf; wT = wcfP; }
        else                 { q -= 294912; w = w_cb; wT = wcbP; }
        int e = q & 3; int o = (q >> 2) % 384; int i = (q / 1536) * 4 + e;
        wT[q] = w[(size_t)o * 384 + i];
    } else if (idx < 4024320) {               // wdbc1P, wdbc2P (56x384)
        int q = idx - 3981312; const float* w; float* wT;
        if (q < 21504) { w = w_dbc1; wT = wdbc1P; }
        else           { q -= 21504; w = w_dbc2; wT = wdbc2P; }
        int e = q & 3; int oc = (q >> 2) % 56; int i = (q / 224) * 4 + e;
        wT[q] = w[(size_t)oc * 384 + i];
    } else if (idx < 4042752) {               // wdt1T, wdt2T
        int q = idx - 4024320; const float* w; float* wT;
        if (q < 9216) { w = w_dt1; wT = wdt1T; }
        else          { q -= 9216; w = w_dt2; wT = wdt2T; }
        int d = q % 384; int qq = q / 384;
        wT[q] = w[(size_t)d * 24 + qq];
    }
}

// ---------------- LN1 -> f32 XNPf + bf16 splits XH/XL, all padded ----------------
__global__ __launch_bounds__(384) void ln1_k(
    const float* __restrict__ x,
    const float* __restrict__ g_n, const float* __restrict__ bt_n,
    float* __restrict__ XNPf, ushort_t* __restrict__ XH, ushort_t* __restrict__ XL)
{
    int blk = blockIdx.x;
    int t = threadIdx.x, wid = t >> 6, lane = t & 63;
    if (blk == MTOT / TM) {
        for (int b = 0; b < NB; ++b) {
            size_t o0 = ((size_t)b * NSP + 0) * ND + t;
            size_t o1 = ((size_t)b * NSP + NS + 1) * ND + t;
            XNPf[o0] = 0.f; XNPf[o1] = 0.f;
            XH[o0] = 0; XL[o0] = 0; XH[o1] = 0; XL[o1] = 0;
        }
        return;
    }
    int m0 = blk * TM;
    int b = m0 >> 10, s0 = m0 & 1023;
    for (int j = wid; j < TM; j += 6) {
        int r = s0 + j;
        const float* row = x + ((size_t)(b * NS + r)) * ND;
        float v[6]; float s1 = 0.f, s2 = 0.f;
        #pragma unroll
        for (int e = 0; e < 6; ++e) {
            v[e] = row[lane + 64 * e];
            s1 += v[e]; s2 += v[e] * v[e];
        }
        #pragma unroll
        for (int o = 32; o; o >>= 1) {
            s1 += __shfl_xor(s1, o);
            s2 += __shfl_xor(s2, o);
        }
        float mu = s1 * (1.f / ND);
        float var = s2 * (1.f / ND) - mu * mu;
        float rs = rsqrtf(var + 1e-5f);
        size_t ob = ((size_t)b * NSP + r + 1) * ND;
        #pragma unroll
        for (int e = 0; e < 6; ++e) {
            int i = lane + 64 * e;
            float val = (v[e] - mu) * rs * g_n[i] + bt_n[i];
            XNPf[ob + i] = val;
            ushort_t hi = f2bf(val);
            XH[ob + i] = hi;
            XL[ob + i] = f2bf(val - bf2f(hi));
        }
    }
}

// ---------------- conv3 x2 as split-bf16 MFMA GEMM, gated, layout-variant ----------------
template<int VAR>
__global__ __launch_bounds__(256) void conv_mfma(
    const int* __restrict__ gate,
    const ushort_t* __restrict__ XH, const ushort_t* __restrict__ XL,
    const ushort_t* __restrict__ Wp,
    const float* __restrict__ b_p2, const float* __restrict__ b_p1,
    float* __restrict__ XP, float* __restrict__ Z1)
{
    if (*((const volatile int*)gate) == 0) return;
    __shared__ ushort_t lds_a[64][40];
    __shared__ ushort_t lds_b[64][40];
    int blk = blockIdx.x;
    int mtile = blk & 63, ntile = blk >> 6;
    int m0 = mtile * 64;
    int b = m0 >> 10, s0 = m0 & 1023;
    int n0 = ntile * 64;
    int t = threadIdx.x;
    int lane = t & 63, w = t >> 6;
    int wr = w >> 1, wc = w & 1;
    int srow = t >> 2;
    int schunk = (t & 3) * 8;
    int kg = (lane >> 4) * 4;

    f32x4 acc[2][2] = {};

    for (int ks = 0; ks < 108; ++ks) {
        int seg = ks / 36;
        int rem = ks - seg * 36;
        int k3 = rem / 12;
        int i0 = (rem - k3 * 12) * 32;
        const ushort_t* XS = (ks < 72) ? XH : XL;
        uint4 av = *reinterpret_cast<const uint4*>(
            XS + ((size_t)(b * NSP + s0 + srow + k3) * ND + i0 + schunk));
        uint4 bv = *reinterpret_cast<const uint4*>(
            Wp + ((size_t)(ntile * 108 + ks) * 2048 + t * 8));
        __syncthreads();
        *reinterpret_cast<uint4*>(&lds_a[srow][schunk]) = av;
        *reinterpret_cast<uint4*>(&lds_b[srow][schunk]) = bv;
        __syncthreads();
        short8 af[2], bf[2];
        #pragma unroll
        for (int mi = 0; mi < 2; ++mi)
            af[mi] = fld(&lds_a[wr * 32 + mi * 16 + (lane & 15)][0], kg, VAR);
        #pragma unroll
        for (int ni = 0; ni < 2; ++ni)
            bf[ni] = fld(&lds_b[wc * 32 + ni * 16 + (lane & 15)][0], kg, VAR);
        #pragma unroll
        for (int mi = 0; mi < 2; ++mi)
            #pragma unroll
            for (int ni = 0; ni < 2; ++ni)
                acc[mi][ni] = __builtin_amdgcn_mfma_f32_16x16x32_bf16(
                    af[mi], bf[ni], acc[mi][ni], 0, 0, 0);
    }

    // epilogue: C col=lane&15, row=(lane>>4)*4+j  (m89, HW-verified)
    #pragma unroll
    for (int mi = 0; mi < 2; ++mi) {
        #pragma unroll
        for (int ni = 0; ni < 2; ++ni) {
            int n = n0 + wc * 32 + ni * 16 + (lane & 15);
            #pragma unroll
            for (int j = 0; j < 4; ++j) {
                int m = m0 + wr * 32 + mi * 16 + (lane >> 4) * 4 + j;
                float v = acc[mi][ni][j];
                if (n < 384) XP[(size_t)m * ND + n] = v + b_p2[n];
                else         Z1[(size_t)m * ND + (n - 384)] = v + b_p1[n - 384];
            }
        }
    }
}

// ---------------- verify: recompute 32 sampled rows (both halves) in f32 ----------------
// 64 blocks x 384 thr; block = (sampled row, matrix half); conv_fb's exact math.
__global__ __launch_bounds__(384) void verify_k(
    const int* __restrict__ gate,
    const float* __restrict__ XNPf,
    const float* __restrict__ wp2P, const float* __restrict__ b_p2,
    const float* __restrict__ wp1P, const float* __restrict__ b_p1,
    const float* __restrict__ XP, const float* __restrict__ Z1,
    int* __restrict__ flagOut)
{
    if (*((const volatile int*)gate) == 0) return;
    int blk = blockIdx.x;                        // 64
    int m = ((blk >> 1) * 131) & 4095;           // 32 distinct spread rows
    int half = blk & 1;
    int b = m >> 10, s0 = m & 1023;
    int t = threadIdx.x;
    const float4* xnp4 = reinterpret_cast<const float4*>(XNPf);
    const float4* wf4 = reinterpret_cast<const float4*>(half ? wp1P : wp2P) + t;
    float a = half ? b_p1[t] : b_p2[t];
    size_t base = (size_t)(b * NSP + s0) * 96;
    for (int kk = 0; kk < 288; ++kk) {
        int k_n = kk / 96, i4 = kk - k_n * 96;
        float4 xv = xnp4[base + (size_t)k_n * 96 + i4];
        float4 W = wf4[(size_t)kk * 384];
        a = fmaf(xv.x, W.x, a);
        a = fmaf(xv.y, W.y, a);
        a = fmaf(xv.z, W.z, a);
        a = fmaf(xv.w, W.w, a);
    }
    float got = half ? Z1[(size_t)m * ND + t] : XP[(size_t)m * ND + t];
    if (fabsf(got - a) > 0.05f) atomicOr(flagOut, 1);
}

// ---------------- fallback conv (verified f32 path), gated on flag ----------
__global__ __launch_bounds__(384) void conv_fb(
    const int* __restrict__ flag,
    const float* __restrict__ XNP,
    const float* __restrict__ wp2P, const float* __restrict__ b_p2,
    const float* __restrict__ wp1P, const float* __restrict__ b_p1,
    float* __restrict__ XP, float* __restrict__ Z1)
{
    if (((const volatile int*)flag)[0] == 0) return;
    int m0 = blockIdx.x * TMC;
    int b = m0 >> 10, s0 = m0 & 1023;
    int t = threadIdx.x;
    const float4* xnp4 = reinterpret_cast<const float4*>(XNP);
    const float4* w2f4 = reinterpret_cast<const float4*>(wp2P) + t;
    const float4* w1f4 = reinterpret_cast<const float4*>(wp1P) + t;

    float a2[TMC], a1[TMC];
    #pragma unroll
    for (int r = 0; r < TMC; ++r) { a2[r] = b_p2[t]; a1[r] = b_p1[t]; }

    size_t base = (size_t)(b * NSP + s0) * 96;
    float4 W2c = w2f4[0], W1c = w1f4[0];
    float4 xc[TMC];
    #pragma unroll
    for (int r = 0; r < TMC; ++r) xc[r] = xnp4[base + (size_t)r * 96];

    for (int kk = 0; kk < 288; ++kk) {
        int kn = (kk < 287) ? kk + 1 : 287;
        float4 W2n = w2f4[(size_t)kn * 384];
        float4 W1n = w1f4[(size_t)kn * 384];
        int k_n = kn / 96, i4_n = kn - k_n * 96;
        size_t rbn = base + (size_t)k_n * 96 + i4_n;
        float4 xn_[TMC];
        #pragma unroll
        for (int r = 0; r < TMC; ++r) xn_[r] = xnp4[rbn + (size_t)r * 96];
        #pragma unroll
        for (int e = 0; e < 4; ++e) {
            float wv2 = fget(W2c, e);
            float wv1 = fget(W1c, e);
            #pragma unroll
            for (int r = 0; r < TMC; ++r) {
                float xe = fget(xc[r], e);
                a2[r] = fmaf(xe, wv2, a2[r]);
                a1[r] = fmaf(xe, wv1, a1[r]);
            }
        }
        W2c = W2n; W1c = W1n;
        #pragma unroll
        for (int r = 0; r < TMC; ++r) xc[r] = xn_[r];
    }
    #pragma unroll
    for (int r = 0; r < TMC; ++r) {
        size_t ix = (size_t)(m0 + r) * ND + t;
        XP[ix] = a2[r];
        Z1[ix] = a1[r];
    }
}

// ---------------- both directions: K=1 conv + LN2 + dbc + delta ----------------
__global__ __launch_bounds__(384) void dir2_k1(
    const float* __restrict__ XP,
    const float* __restrict__ wcfP, const float* __restrict__ b_cf,
    const float* __restrict__ g_nf, const float* __restrict__ bt_nf,
    const float* __restrict__ wdbc1P, const float* __restrict__ wdt1T,
    const float* __restrict__ b_dt1,
    const float* __restrict__ wcbP, const float* __restrict__ b_cb,
    const float* __restrict__ g_nb, const float* __restrict__ bt_nb,
    const float* __restrict__ wdbc2P, const float* __restrict__ wdt2T,
    const float* __restrict__ b_dt2,
    float* __restrict__ LN2, float* __restrict__ DBC2, float* __restrict__ DEL2)
{
    __shared__ float uo[TM][ND];
    __shared__ float red[TM][6][2];
    __shared__ float dbcS[TM][56];
    int blk = blockIdx.x;
    int dir = blk >> 9;
    int m0 = (blk & 511) * TM;
    int b = m0 >> 10, s0 = m0 & 1023;
    int t = threadIdx.x, wid = t >> 6, lane = t & 63;

    const float* wcP   = dir ? wcbP   : wcfP;
    const float* b_c   = dir ? b_cb   : b_cf;
    const float* g     = dir ? g_nb   : g_nf;
    const float* bt    = dir ? bt_nb  : bt_nf;
    const float* wdbcP = dir ? wdbc2P : wdbc1P;
    const float* wdtT  = dir ? wdt2T  : wdt1T;
    const float* b_dt  = dir ? b_dt2  : b_dt1;
    const size_t NM = (size_t)MTOT * ND;
    float* LNo  = LN2  + (size_t)dir * NM;
    float* DBCo = DBC2 + (size_t)dir * MTOT * 56;
    float* DELo = DEL2 + (size_t)dir * NM;

    const float4* XPf4 = reinterpret_cast<const float4*>(XP);
    size_t rowb[TM];
    #pragma unroll
    for (int r = 0; r < TM; ++r) {
        int s = s0 + r;
        int sE = dir ? (NS - 1 - s) : s;
        rowb[r] = ((size_t)(b * NS + sE)) * 96;
    }

    const float4* wcf4 = reinterpret_cast<const float4*>(wcP) + t;
    float acc[TM];
    #pragma unroll
    for (int r = 0; r < TM; ++r) acc[r] = b_c[t];
    float4 Wc = wcf4[0];
    float4 xc[TM];
    #pragma unroll
    for (int r = 0; r < TM; ++r) xc[r] = XPf4[rowb[r]];
    for (int i4 = 0; i4 < 96; ++i4) {
        int in_ = (i4 < 95) ? i4 + 1 : 95;
        float4 Wn = wcf4[(size_t)in_ * 384];
        float4 xn_[TM];
        #pragma unroll
        for (int r = 0; r < TM; ++r) xn_[r] = XPf4[rowb[r] + in_];
        #pragma unroll
        for (int e = 0; e < 4; ++e) {
            float wv = fget(Wc, e);
            #pragma unroll
            for (int r = 0; r < TM; ++r)
                acc[r] = fmaf(fget(xc[r], e), wv, acc[r]);
        }
        Wc = Wn;
        #pragma unroll
        for (int r = 0; r < TM; ++r) xc[r] = xn_[r];
    }

    #pragma unroll
    for (int r = 0; r < TM; ++r) {
        float s1 = acc[r], s2 = acc[r] * acc[r];
        #pragma unroll
        for (int o = 32; o; o >>= 1) {
            s1 += __shfl_xor(s1, o);
            s2 += __shfl_xor(s2, o);
        }
        if (lane == 0) { red[r][wid][0] = s1; red[r][wid][1] = s2; }
    }
    __syncthreads();
    float gt = g[t], btt = bt[t];
    #pragma unroll
    for (int r = 0; r < TM; ++r) {
        float s1 = 0.f, s2 = 0.f;
        #pragma unroll
        for (int w = 0; w < 6; ++w) { s1 += red[r][w][0]; s2 += red[r][w][1]; }
        float mu = s1 * (1.f / ND);
        float var = s2 * (1.f / ND) - mu * mu;
        float rs = rsqrtf(var + 1e-5f);
        float ln = (acc[r] - mu) * rs * gt + btt;
        uo[r][t] = ln;
        LNo[(size_t)(m0 + r) * ND + t] = ln;
    }
    __syncthreads();

    for (int r = wid; r < TM; r += 6) {
        if (lane < 56) {
            const float4* wdf4 = reinterpret_cast<const float4*>(wdbcP) + lane;
            const float4* uof4 = reinterpret_cast<const float4*>(&uo[r][0]);
            float a = 0.f;
            float4 Wd = wdf4[0];
            for (int i4 = 0; i4 < 96; ++i4) {
                int in_ = (i4 < 95) ? i4 + 1 : 95;
                float4 Wdn = wdf4[(size_t)in_ * 56];
                float4 uv = uof4[i4];
                a = fmaf(uv.x, Wd.x, a);
                a = fmaf(uv.y, Wd.y, a);
                a = fmaf(uv.z, Wd.z, a);
                a = fmaf(uv.w, Wd.w, a);
                Wd = Wdn;
            }
            dbcS[r][lane] = a;
            DBCo[(size_t)(m0 + r) * 56 + lane] = a;
        }
    }
    __syncthreads();

    float accD[TM]; float bd = b_dt[t];
    #pragma unroll
    for (int r = 0; r < TM; ++r) accD[r] = bd;
    for (int q = 0; q < 24; ++q) {
        float wv = wdtT[q * 384 + t];
        #pragma unroll
        for (int r = 0; r < TM; ++r) accD[r] = fmaf(dbcS[r][q], wv, accD[r]);
    }
    #pragma unroll
    for (int r = 0; r < TM; ++r) {
        float a = accD[r];
        DELo[(size_t)(m0 + r) * ND + t] =
            fmaxf(a, 0.f) + log1pf(__expf(-fabsf(a)));
    }
}

// ---------------- parallel scan ----------------
__global__ __launch_bounds__(384) void scan_s1(
    const float* __restrict__ DEL2, const float* __restrict__ LN2,
    const float* __restrict__ DBC2, const float* __restrict__ A_log1,
    const float* __restrict__ A_log2,
    float* __restrict__ P, float* __restrict__ H)
{
    __shared__ float bc[CHL][32];
    int blk = blockIdx.x;
    int c = blk & (NCH - 1);
    int db = blk >> 5;
    int dir = db >> 2, b = db & 3;
    int t = threadIdx.x;
    const float* del  = DEL2 + (size_t)dir * MTOT * ND;
    const float* u    = LN2  + (size_t)dir * MTOT * ND;
    const float* dbc  = DBC2 + (size_t)dir * MTOT * 56;
    const float* Alog = dir ? A_log2 : A_log1;

    for (int e = t; e < CHL * 32; e += 384) {
        int row = e >> 5, col = e & 31;
        bc[row][col] = dbc[((size_t)(b * NS + c * CHL + row)) * 56 + 24 + col];
    }
    __syncthreads();

    float A[NN], h[NN], p[NN];
    #pragma unroll
    for (int n = 0; n < NN; ++n) {
        A[n] = -__expf(Alog[(size_t)t * NN + n]);
        h[n] = 0.f; p[n] = 1.f;
    }
    for (int j = 0; j < CHL; ++j) {
        size_t rix = (size_t)b * NS + c * CHL + j;
        float dl = del[rix * ND + t];
        float uv = u[rix * ND + t];
        float dx = dl * uv;
        #pragma unroll
        for (int n = 0; n < NN; ++n) {
            float da = __expf(dl * A[n]);
            h[n] = fmaf(da, h[n], dx * bc[j][n]);
            p[n] *= da;
        }
    }
    size_t base = ((size_t)blk * ND + t) * NN;
    #pragma unroll
    for (int n = 0; n < NN; ++n) { P[base + n] = p[n]; H[base + n] = h[n]; }
}

__global__ __launch_bounds__(256) void scan_s2(
    float* __restrict__ P, const float* __restrict__ H)
{
    int gid = blockIdx.x * 256 + threadIdx.x;
    int n = gid & 15;
    int d = (gid >> 4) % ND;
    int db = gid / (16 * ND);
    float h = 0.f;
    for (int c = 0; c < NCH; ++c) {
        size_t idx = (((size_t)db * NCH + c) * ND + d) * NN + n;
        float p = P[idx];
        float hh = H[idx];
        P[idx] = h;
        h = fmaf(p, h, hh);
    }
}

__global__ __launch_bounds__(384) void scan_s3(
    const float* __restrict__ DEL2, const float* __restrict__ LN2,
    const float* __restrict__ DBC2, const float* __restrict__ A_log1,
    const float* __restrict__ A_log2, const float* __restrict__ D1,
    const float* __restrict__ D2, const float* __restrict__ Hinit,
    float* __restrict__ Y2)
{
    __shared__ float bc[CHL][32];
    int blk = blockIdx.x;
    int c = blk & (NCH - 1);
    int db = blk >> 5;
    int dir = db >> 2, b = db & 3;
    int t = threadIdx.x;
    const float* del  = DEL2 + (size_t)dir * MTOT * ND;
    const float* u    = LN2  + (size_t)dir * MTOT * ND;
    const float* dbc  = DBC2 + (size_t)dir * MTOT * 56;
    const float* Alog = dir ? A_log2 : A_log1;
    const float* Dv   = dir ? D2 : D1;
    float* y          = Y2 + (size_t)dir * MTOT * ND;

    for (int e = t; e < CHL * 32; e += 384) {
        int row = e >> 5, col = e & 31;
        bc[row][col] = dbc[((size_t)(b * NS + c * CHL + row)) * 56 + 24 + col];
    }
    __syncthreads();

    size_t base = ((size_t)blk * ND + t) * NN;
    float A[NN], h[NN];
    #pragma unroll
    for (int n = 0; n < NN; ++n) {
        A[n] = -__expf(Alog[(size_t)t * NN + n]);
        h[n] = Hinit[base + n];
    }
    float Dd = Dv[t];
    for (int j = 0; j < CHL; ++j) {
        size_t rix = (size_t)b * NS + c * CHL + j;
        float dl = del[rix * ND + t];
        float uv = u[rix * ND + t];
        float dx = dl * uv;
        float y0 = 0.f, y1 = 0.f;
        #pragma unroll
        for (int n = 0; n < NN; n += 2) {
            float da0 = __expf(dl * A[n]);
            float da1 = __expf(dl * A[n + 1]);
            h[n]     = fmaf(da0, h[n],     dx * bc[j][n]);
            h[n + 1] = fmaf(da1, h[n + 1], dx * bc[j][n + 1]);
            y0 = fmaf(h[n],     bc[j][16 + n],     y0);
            y1 = fmaf(h[n + 1], bc[j][16 + n + 1], y1);
        }
        y[rix * ND + t] = y0 + y1 + Dd * uv;
    }
}

// ---------------- gate: X3 = (YF+YB) * silu(Z1) ----------------
__global__ __launch_bounds__(256) void gate_k(
    const float* __restrict__ Z1, const float* __restrict__ YF,
    const float* __restrict__ YB, float* __restrict__ X3)
{
    int i = blockIdx.x * 256 + threadIdx.x;
    const float4* z4 = reinterpret_cast<const float4*>(Z1);
    const float4* f4 = reinterpret_cast<const float4*>(YF);
    const float4* b4 = reinterpret_cast<const float4*>(YB);
    float4* o4 = reinterpret_cast<float4*>(X3);
    float4 z = z4[i], f = f4[i], bb = b4[i], o;
    o.x = (f.x + bb.x) * (z.x / (1.f + __expf(-z.x)));
    o.y = (f.y + bb.y) * (z.y / (1.f + __expf(-z.y)));
    o.z = (f.z + bb.z) * (z.z / (1.f + __expf(-z.z)));
    o.w = (f.w + bb.w) * (z.w / (1.f + __expf(-z.w)));
    o4[i] = o;
}

// ---------------- final projection + skip ----------------
__global__ __launch_bounds__(384) void final_k(
    const float* __restrict__ x, const float* __restrict__ X3,
    const float* __restrict__ wp3P, const float* __restrict__ b_p3,
    float* __restrict__ out)
{
    int m0 = blockIdx.x * TMC;
    int t = threadIdx.x;
    const float4* x3f4 = reinterpret_cast<const float4*>(X3);
    const float4* wpf4 = reinterpret_cast<const float4*>(wp3P) + t;
    size_t rb = (size_t)m0 * 96;

    float acc[TMC]; float bp = b_p3[t];
    #pragma unroll
    for (int r = 0; r < TMC; ++r) acc[r] = bp;
    float4 Wp = wpf4[0];
    float4 xc[TMC];
    #pragma unroll
    for (int r = 0; r < TMC; ++r) xc[r] = x3f4[rb + (size_t)r * 96];
    for (int i4 = 0; i4 < 96; ++i4) {
        int in_ = (i4 < 95) ? i4 + 1 : 95;
        float4 Wn = wpf4[(size_t)in_ * 384];
        float4 xn_[TMC];
        #pragma unroll
        for (int r = 0; r < TMC; ++r) xn_[r] = x3f4[rb + (size_t)r * 96 + in_];
        #pragma unroll
        for (int e = 0; e < 4; ++e) {
            float wv = fget(Wp, e);
            #pragma unroll
            for (int r = 0; r < TMC; ++r)
                acc[r] = fmaf(fget(xc[r], e), wv, acc[r]);
        }
        Wp = Wn;
        #pragma unroll
        for (int r = 0; r < TMC; ++r) xc[r] = xn_[r];
    }
    #pragma unroll
    for (int r = 0; r < TMC; ++r) {
        size_t ix = (size_t)(m0 + r) * ND + t;
        out[ix] = acc[r] + x[ix];
    }
}

__global__ __launch_bounds__(256) void fill_f32(float* out, float v, int n)
{
    int i = blockIdx.x * 256 + threadIdx.x;
    if (i < n) out[i] = v;
}

// ---------------- launch ----------------
extern "C" void kernel_launch(void* const* d_in, const int* in_sizes, int n_in,
                              void* d_out, int out_size, void* d_ws, size_t ws_size,
                              hipStream_t stream) {
    float* out = (float*)d_out;

    if (out_size != MTOT * ND) {
        fill_f32<<<(out_size + 255) / 256, 256, 0, stream>>>(
            out, 70000.f + (float)(out_size >> 16), out_size);
        return;
    }

    const float* x      = (const float*)d_in[0];
    const float* w_p1   = (const float*)d_in[1];
    const float* b_p1   = (const float*)d_in[2];
    const float* w_p2   = (const float*)d_in[3];
    const float* b_p2   = (const float*)d_in[4];
    const float* w_p3   = (const float*)d_in[5];
    const float* b_p3   = (const float*)d_in[6];
    const float* w_cf   = (const float*)d_in[7];
    const float* b_cf   = (const float*)d_in[8];
    const float* w_cb   = (const float*)d_in[9];
    const float* b_cb   = (const float*)d_in[10];
    const float* g_n    = (const float*)d_in[11];
    const float* bt_n   = (const float*)d_in[12];
    const float* g_nf   = (const float*)d_in[13];
    const float* bt_nf  = (const float*)d_in[14];
    const float* g_nb   = (const float*)d_in[15];
    const float* bt_nb  = (const float*)d_in[16];
    const float* w_dbc1 = (const float*)d_in[17];
    const float* w_dt1  = (const float*)d_in[18];
    const float* b_dt1  = (const float*)d_in[19];
    const float* A_log1 = (const float*)d_in[20];
    const float* D1     = (const float*)d_in[21];
    const float* w_dbc2 = (const float*)d_in[22];
    const float* w_dt2  = (const float*)d_in[23];
    const float* b_dt2  = (const float*)d_in[24];
    const float* A_log2 = (const float*)d_in[25];
    const float* D2     = (const float*)d_in[26];

    const size_t NM = (size_t)MTOT * ND;
    const size_t N56 = (size_t)MTOT * 56;
    const size_t AGG = (size_t)2 * NB * NCH * ND * NN;
    size_t off = 0;
    float* ws = (float*)d_ws;
    float* XP    = ws + off; off += NM;
    float* Z1    = ws + off; off += NM;
    float* LN2   = ws + off; off += 2 * NM;
    float* DEL2  = ws + off; off += 2 * NM;
    float* Y2    = ws + off; off += 2 * NM;
    float* DBC2  = ws + off; off += 2 * N56;
    float* wp1P   = ws + off; off += 442368;
    float* wp2P   = ws + off; off += 442368;
    float* wp3P   = ws + off; off += 147456;
    float* wcfP   = ws + off; off += 147456;
    float* wcbP   = ws + off; off += 147456;
    float* wdbc1P = ws + off; off += 21504;
    float* wdbc2P = ws + off; off += 21504;
    float* wdt1T  = ws + off; off += 9216;
    float* wdt2T  = ws + off; off += 9216;
    float* Pagg  = ws + off; off += AGG;
    float* Hagg  = ws + off; off += AGG;
    const size_t ws_need = off;

    if (ws_size < ws_need * sizeof(float)) {
        fill_f32<<<(out_size + 255) / 256, 256, 0, stream>>>(out, 60000.f, out_size);
        return;
    }

    float* YF   = Y2;         float* YB   = Y2 + NM;
    // aliases (stream-ordered, lifetimes disjoint):
    // XH/XL (bf16) in Y2 until conv done (scan_s3 writes Y2 later).
    // XNPf (f32 padded LN1) in DEL2 until conv_fb done (dir2 writes DEL2 later).
    // Wp (bf16 weights) in Hagg until conv done (scan_s1 writes H later).
    // flags in Pagg[0..2] until conv_fb done (scan_s1 writes P later).
    ushort_t* XH = (ushort_t*)Y2;
    ushort_t* XL = XH + (size_t)NB * NSP * ND;
    float* XNPf = DEL2;
    ushort_t* Wp = (ushort_t*)Hagg;
    int* flag1 = (int*)Pagg;          // v0 bad?
    int* flag2 = (int*)Pagg + 1;      // v1 also bad?
    int* galways = (int*)Pagg + 2;    // nonzero constant
    float* X3  = DEL2;

    prep_weights<<<15792, 256, 0, stream>>>(
        w_p1, w_p2, w_p3, w_cf, w_cb, w_dbc1, w_dbc2, w_dt1, w_dt2,
        Wp, wp1P, wp2P, wp3P, wcfP, wcbP, wdbc1P, wdbc2P, wdt1T, wdt2T);

    fill_f32<<<1, 256, 0, stream>>>((float*)Pagg, 0.f, 2);
    fill_f32<<<1, 256, 0, stream>>>((float*)Pagg + 2, 1.f, 1);

    ln1_k<<<MTOT / TM + 1, 384, 0, stream>>>(x, g_n, bt_n, XNPf, XH, XL);

    // V0: interleaved K=16 halves (tr-read-derived layout)
    conv_mfma<0><<<64 * 12, 256, 0, stream>>>(
        galways, XH, XL, Wp, b_p2, b_p1, XP, Z1);
    verify_k<<<64, 384, 0, stream>>>(
        galways, XNPf, wp2P, b_p2, wp1P, b_p1, XP, Z1, flag1);

    // V1: swapped half order (only if V0 failed)
    conv_mfma<1><<<64 * 12, 256, 0, stream>>>(
        flag1, XH, XL, Wp, b_p2, b_p1, XP, Z1);
    verify_k<<<64, 384, 0, stream>>>(
        flag1, XNPf, wp2P, b_p2, wp1P, b_p1, XP, Z1, flag2);

    // f32 fallback (only if both variants failed)
    conv_fb<<<MTOT / TMC, 384, 0, stream>>>(
        flag2, XNPf, wp2P, b_p2, wp1P, b_p1, XP, Z1);

    dir2_k1<<<2 * (MTOT / TM), 384, 0, stream>>>(
        XP,
        wcfP, b_cf, g_nf, bt_nf, wdbc1P, wdt1T, b_dt1,
        wcbP, b_cb, g_nb, bt_nb, wdbc2P, wdt2T, b_dt2,
        LN2, DBC2, DEL2);

    scan_s1<<<2 * NB * NCH, 384, 0, stream>>>(
        DEL2, LN2, DBC2, A_log1, A_log2, Pagg, Hagg);
    scan_s2<<<(2 * NB * ND * NN) / 256, 256, 0, stream>>>(Pagg, Hagg);
    scan_s3<<<2 * NB * NCH, 384, 0, stream>>>(
        DEL2, LN2, DBC2, A_log1, A_log2, D1, D2, Pagg, Y2);

    gate_k<<<(int)(NM / 4 / 256), 256, 0, stream>>>(Z1, YF, YB, X3);

    final_k<<<MTOT / TMC, 384, 0, stream>>>(
        x, X3, wp3P, b_p3, out);
}

// Round 11
// 614.755 us; speedup vs baseline: 1.0587x; 1.0287x over previous
//
#include <hip/hip_runtime.h>
#include <cstddef>

#define NB 4
#define NS 1024
#define ND 384
#define NN 16
#define MTOT 4096
#define TM 8    // rows per block (dir2_k1, ln1)
#define TMC 4   // rows per block (fallback conv, final_k)
#define NCH 32
#define CHL 32
#define NSP (NS + 2)

typedef unsigned short ushort_t;
typedef __attribute__((ext_vector_type(8))) short short8;
typedef __attribute__((ext_vector_type(4))) short short4v;
typedef __attribute__((ext_vector_type(4))) float f32x4;

static __device__ __forceinline__ float fget(const float4& v, int e) {
    return e == 0 ? v.x : e == 1 ? v.y : e == 2 ? v.z : v.w;
}
static __device__ __forceinline__ ushort_t f2bf(float x) {
    unsigned u = __float_as_uint(x);
    return (ushort_t)((u + 0x7FFF + ((u >> 16) & 1)) >> 16);
}
static __device__ __forceinline__ float bf2f(ushort_t h) {
    return __uint_as_float(((unsigned)h) << 16);
}

// Fragment k-gather modes for mfma_f32_16x16x32_bf16, row = lane&15, g = lane>>4:
//  MODE 0: contiguous-8   : elem e <- k = 8g + e
//  MODE 1: interleaved K16: elem e<4 <- k = 4g+e ; e>=4 <- k = 16+4g+(e-4)
//          (tr-read-derived, m156/m162)
template<int MODE>
static __device__ __forceinline__ short8 fldm(const ushort_t* rowp, int g) {
    if (MODE == 0) {
        return *reinterpret_cast<const short8*>(rowp + g * 8);
    } else {
        const short4v* p0 = reinterpret_cast<const short4v*>(rowp + g * 4);
        const short4v* p1 = reinterpret_cast<const short4v*>(rowp + 16 + g * 4);
        return __builtin_shufflevector(*p0, *p1, 0, 1, 2, 3, 4, 5, 6, 7);
    }
}

// ---------------- weight packing ----------------
__global__ __launch_bounds__(256) void prep_weights(
    const float* __restrict__ w_p1, const float* __restrict__ w_p2,
    const float* __restrict__ w_p3, const float* __restrict__ w_cf,
    const float* __restrict__ w_cb,
    const float* __restrict__ w_dbc1, const float* __restrict__ w_dbc2,
    const float* __restrict__ w_dt1,  const float* __restrict__ w_dt2,
    ushort_t* __restrict__ Wp,
    float* __restrict__ wp1P, float* __restrict__ wp2P,
    float* __restrict__ wp3P, float* __restrict__ wcfP, float* __restrict__ wcbP,
    float* __restrict__ wdbc1P, float* __restrict__ wdbc2P,
    float* __restrict__ wdt1T,  float* __restrict__ wdt2T)
{
    int idx = blockIdx.x * 256 + threadIdx.x;
    if (idx < 2654208) {                      // Wp bf16 (hi/lo segments)
        int kc = idx & 31; int nr = (idx >> 5) & 63; int chunk = idx >> 11;
        int ks = chunk % 108; int nblk = chunk / 108;
        int n = nblk * 64 + nr;
        int keff = ks * 32 + kc;
        int seg = keff / 1152; int r = keff - seg * 1152;
        int k3 = r / 384; int i = r - k3 * 384;
        const float* mat = (n < 384) ? w_p2 : w_p1;
        float v = mat[((size_t)(n & 383) * 384 + i) * 3 + k3];
        ushort_t hi = f2bf(v);
        ushort_t outv = hi;
        if (seg == 1) outv = f2bf(v - bf2f(hi));
        Wp[idx] = outv;
    } else if (idx < 3538944) {               // wp1P, wp2P f32 (fallback conv)
        int q = idx - 2654208; const float* w; float* wT;
        if (q < 442368) { w = w_p1; wT = wp1P; }
        else            { q -= 442368; w = w_p2; wT = wp2P; }
        int e = q & 3; int o = (q >> 2) % 384; int kk = q / 1536;
        int k = kk / 96; int i = (kk % 96) * 4 + e;
        wT[q] = w[((size_t)o * 384 + i) * 3 + k];
    } else if (idx < 3981312) {               // wp3P, wcfP, wcbP (384x384)
        int q = idx - 3538944; const float* w; float* wT;
        if (q < 147456)      { w = w_p3; wT = wp3P; }
        else if (q < 294912) { q -= 147456; w = w_cf; wT = wcfP; }
        else                 { q -= 294912; w = w_cb; wT = wcbP; }
        int e = q & 3; int o = (q >> 2) % 384; int i = (q / 1536) * 4 + e;
        wT[q] = w[(size_t)o * 384 + i];
    } else if (idx < 4024320) {               // wdbc1P, wdbc2P (56x384)
        int q = idx - 3981312; const float* w; float* wT;
        if (q < 21504) { w = w_dbc1; wT = wdbc1P; }
        else           { q -= 21504; w = w_dbc2; wT = wdbc2P; }
        int e = q & 3; int oc = (q >> 2) % 56; int i = (q / 224) * 4 + e;
        wT[q] = w[(size_t)oc * 384 + i];
    } else if (idx < 4042752) {               // wdt1T, wdt2T
        int q = idx - 4024320; const float* w; float* wT;
        if (q < 9216) { w = w_dt1; wT = wdt1T; }
        else          { q -= 9216; w = w_dt2; wT = wdt2T; }
        int d = q % 384; int qq = q / 384;
        wT[q] = w[(size_t)d * 24 + qq];
    }
}

// ---------------- LN1 -> f32 XNPf + bf16 splits XH/XL, all padded ----------------
__global__ __launch_bounds__(384) void ln1_k(
    const float* __restrict__ x,
    const float* __restrict__ g_n, const float* __restrict__ bt_n,
    float* __restrict__ XNPf, ushort_t* __restrict__ XH, ushort_t* __restrict__ XL)
{
    int blk = blockIdx.x;
    int t = threadIdx.x, wid = t >> 6, lane = t & 63;
    if (blk == MTOT / TM) {
        for (int b = 0; b < NB; ++b) {
            size_t o0 = ((size_t)b * NSP + 0) * ND + t;
            size_t o1 = ((size_t)b * NSP + NS + 1) * ND + t;
            XNPf[o0] = 0.f; XNPf[o1] = 0.f;
            XH[o0] = 0; XL[o0] = 0; XH[o1] = 0; XL[o1] = 0;
        }
        return;
    }
    int m0 = blk * TM;
    int b = m0 >> 10, s0 = m0 & 1023;
    for (int j = wid; j < TM; j += 6) {
        int r = s0 + j;
        const float* row = x + ((size_t)(b * NS + r)) * ND;
        float v[6]; float s1 = 0.f, s2 = 0.f;
        #pragma unroll
        for (int e = 0; e < 6; ++e) {
            v[e] = row[lane + 64 * e];
            s1 += v[e]; s2 += v[e] * v[e];
        }
        #pragma unroll
        for (int o = 32; o; o >>= 1) {
            s1 += __shfl_xor(s1, o);
            s2 += __shfl_xor(s2, o);
        }
        float mu = s1 * (1.f / ND);
        float var = s2 * (1.f / ND) - mu * mu;
        float rs = rsqrtf(var + 1e-5f);
        size_t ob = ((size_t)b * NSP + r + 1) * ND;
        #pragma unroll
        for (int e = 0; e < 6; ++e) {
            int i = lane + 64 * e;
            float val = (v[e] - mu) * rs * g_n[i] + bt_n[i];
            XNPf[ob + i] = val;
            ushort_t hi = f2bf(val);
            XH[ob + i] = hi;
            XL[ob + i] = f2bf(val - bf2f(hi));
        }
    }
}

// ---------------- conv3 x2 as split-bf16 MFMA GEMM, gated, asymmetric gathers ------
template<int AMODE, int BMODE>
__global__ __launch_bounds__(256) void conv_mfma(
    const int* __restrict__ gate,
    const ushort_t* __restrict__ XH, const ushort_t* __restrict__ XL,
    const ushort_t* __restrict__ Wp,
    const float* __restrict__ b_p2, const float* __restrict__ b_p1,
    float* __restrict__ XP, float* __restrict__ Z1)
{
    if (*((const volatile int*)gate) == 0) return;
    __shared__ ushort_t lds_a[64][40];
    __shared__ ushort_t lds_b[64][40];
    int blk = blockIdx.x;
    int mtile = blk & 63, ntile = blk >> 6;
    int m0 = mtile * 64;
    int b = m0 >> 10, s0 = m0 & 1023;
    int n0 = ntile * 64;
    int t = threadIdx.x;
    int lane = t & 63, w = t >> 6;
    int wr = w >> 1, wc = w & 1;
    int srow = t >> 2;
    int schunk = (t & 3) * 8;
    int g = lane >> 4;

    f32x4 acc[2][2] = {};

    for (int ks = 0; ks < 108; ++ks) {
        int seg = ks / 36;
        int rem = ks - seg * 36;
        int k3 = rem / 12;
        int i0 = (rem - k3 * 12) * 32;
        const ushort_t* XS = (ks < 72) ? XH : XL;
        uint4 av = *reinterpret_cast<const uint4*>(
            XS + ((size_t)(b * NSP + s0 + srow + k3) * ND + i0 + schunk));
        uint4 bv = *reinterpret_cast<const uint4*>(
            Wp + ((size_t)(ntile * 108 + ks) * 2048 + t * 8));
        __syncthreads();
        *reinterpret_cast<uint4*>(&lds_a[srow][schunk]) = av;
        *reinterpret_cast<uint4*>(&lds_b[srow][schunk]) = bv;
        __syncthreads();
        short8 af[2], bf[2];
        #pragma unroll
        for (int mi = 0; mi < 2; ++mi)
            af[mi] = fldm<AMODE>(&lds_a[wr * 32 + mi * 16 + (lane & 15)][0], g);
        #pragma unroll
        for (int ni = 0; ni < 2; ++ni)
            bf[ni] = fldm<BMODE>(&lds_b[wc * 32 + ni * 16 + (lane & 15)][0], g);
        #pragma unroll
        for (int mi = 0; mi < 2; ++mi)
            #pragma unroll
            for (int ni = 0; ni < 2; ++ni)
                acc[mi][ni] = __builtin_amdgcn_mfma_f32_16x16x32_bf16(
                    af[mi], bf[ni], acc[mi][ni], 0, 0, 0);
    }

    // epilogue: C col=lane&15 (N side / arg1), row=(lane>>4)*4+j (M side / arg0) — m89
    #pragma unroll
    for (int mi = 0; mi < 2; ++mi) {
        #pragma unroll
        for (int ni = 0; ni < 2; ++ni) {
            int n = n0 + wc * 32 + ni * 16 + (lane & 15);
            #pragma unroll
            for (int j = 0; j < 4; ++j) {
                int m = m0 + wr * 32 + mi * 16 + (lane >> 4) * 4 + j;
                float v = acc[mi][ni][j];
                if (n < 384) XP[(size_t)m * ND + n] = v + b_p2[n];
                else         Z1[(size_t)m * ND + (n - 384)] = v + b_p1[n - 384];
            }
        }
    }
}

// ---------------- verify: recompute 32 sampled rows (both halves) in f32 ----------------
__global__ __launch_bounds__(384) void verify_k(
    const int* __restrict__ gate,
    const float* __restrict__ XNPf,
    const float* __restrict__ wp2P, const float* __restrict__ b_p2,
    const float* __restrict__ wp1P, const float* __restrict__ b_p1,
    const float* __restrict__ XP, const float* __restrict__ Z1,
    int* __restrict__ flagOut)
{
    if (*((const volatile int*)gate) == 0) return;
    int blk = blockIdx.x;                        // 64
    int m = ((blk >> 1) * 131) & 4095;           // 32 distinct spread rows
    int half = blk & 1;
    int b = m >> 10, s0 = m & 1023;
    int t = threadIdx.x;
    const float4* xnp4 = reinterpret_cast<const float4*>(XNPf);
    const float4* wf4 = reinterpret_cast<const float4*>(half ? wp1P : wp2P) + t;
    float a = half ? b_p1[t] : b_p2[t];
    size_t base = (size_t)(b * NSP + s0) * 96;
    for (int kk = 0; kk < 288; ++kk) {
        int k_n = kk / 96, i4 = kk - k_n * 96;
        float4 xv = xnp4[base + (size_t)k_n * 96 + i4];
        float4 W = wf4[(size_t)kk * 384];
        a = fmaf(xv.x, W.x, a);
        a = fmaf(xv.y, W.y, a);
        a = fmaf(xv.z, W.z, a);
        a = fmaf(xv.w, W.w, a);
    }
    float got = half ? Z1[(size_t)m * ND + t] : XP[(size_t)m * ND + t];
    if (fabsf(got - a) > 0.05f) atomicOr(flagOut, 1);
}

// ---------------- fallback conv (verified f32 path), gated on flag ----------
__global__ __launch_bounds__(384) void conv_fb(
    const int* __restrict__ flag,
    const float* __restrict__ XNP,
    const float* __restrict__ wp2P, const float* __restrict__ b_p2,
    const float* __restrict__ wp1P, const float* __restrict__ b_p1,
    float* __restrict__ XP, float* __restrict__ Z1)
{
    if (((const volatile int*)flag)[0] == 0) return;
    int m0 = blockIdx.x * TMC;
    int b = m0 >> 10, s0 = m0 & 1023;
    int t = threadIdx.x;
    const float4* xnp4 = reinterpret_cast<const float4*>(XNP);
    const float4* w2f4 = reinterpret_cast<const float4*>(wp2P) + t;
    const float4* w1f4 = reinterpret_cast<const float4*>(wp1P) + t;

    float a2[TMC], a1[TMC];
    #pragma unroll
    for (int r = 0; r < TMC; ++r) { a2[r] = b_p2[t]; a1[r] = b_p1[t]; }

    size_t base = (size_t)(b * NSP + s0) * 96;
    float4 W2c = w2f4[0], W1c = w1f4[0];
    float4 xc[TMC];
    #pragma unroll
    for (int r = 0; r < TMC; ++r) xc[r] = xnp4[base + (size_t)r * 96];

    for (int kk = 0; kk < 288; ++kk) {
        int kn = (kk < 287) ? kk + 1 : 287;
        float4 W2n = w2f4[(size_t)kn * 384];
        float4 W1n = w1f4[(size_t)kn * 384];
        int k_n = kn / 96, i4_n = kn - k_n * 96;
        size_t rbn = base + (size_t)k_n * 96 + i4_n;
        float4 xn_[TMC];
        #pragma unroll
        for (int r = 0; r < TMC; ++r) xn_[r] = xnp4[rbn + (size_t)r * 96];
        #pragma unroll
        for (int e = 0; e < 4; ++e) {
            float wv2 = fget(W2c, e);
            float wv1 = fget(W1c, e);
            #pragma unroll
            for (int r = 0; r < TMC; ++r) {
                float xe = fget(xc[r], e);
                a2[r] = fmaf(xe, wv2, a2[r]);
                a1[r] = fmaf(xe, wv1, a1[r]);
            }
        }
        W2c = W2n; W1c = W1n;
        #pragma unroll
        for (int r = 0; r < TMC; ++r) xc[r] = xn_[r];
    }
    #pragma unroll
    for (int r = 0; r < TMC; ++r) {
        size_t ix = (size_t)(m0 + r) * ND + t;
        XP[ix] = a2[r];
        Z1[ix] = a1[r];
    }
}

// ---------------- both directions: K=1 conv + LN2 + dbc + delta ----------------
__global__ __launch_bounds__(384) void dir2_k1(
    const float* __restrict__ XP,
    const float* __restrict__ wcfP, const float* __restrict__ b_cf,
    const float* __restrict__ g_nf, const float* __restrict__ bt_nf,
    const float* __restrict__ wdbc1P, const float* __restrict__ wdt1T,
    const float* __restrict__ b_dt1,
    const float* __restrict__ wcbP, const float* __restrict__ b_cb,
    const float* __restrict__ g_nb, const float* __restrict__ bt_nb,
    const float* __restrict__ wdbc2P, const float* __restrict__ wdt2T,
    const float* __restrict__ b_dt2,
    float* __restrict__ LN2, float* __restrict__ DBC2, float* __restrict__ DEL2)
{
    __shared__ float uo[TM][ND];
    __shared__ float red[TM][6][2];
    __shared__ float dbcS[TM][56];
    int blk = blockIdx.x;
    int dir = blk >> 9;
    int m0 = (blk & 511) * TM;
    int b = m0 >> 10, s0 = m0 & 1023;
    int t = threadIdx.x, wid = t >> 6, lane = t & 63;

    const float* wcP   = dir ? wcbP   : wcfP;
    const float* b_c   = dir ? b_cb   : b_cf;
    const float* g     = dir ? g_nb   : g_nf;
    const float* bt    = dir ? bt_nb  : bt_nf;
    const float* wdbcP = dir ? wdbc2P : wdbc1P;
    const float* wdtT  = dir ? wdt2T  : wdt1T;
    const float* b_dt  = dir ? b_dt2  : b_dt1;
    const size_t NM = (size_t)MTOT * ND;
    float* LNo  = LN2  + (size_t)dir * NM;
    float* DBCo = DBC2 + (size_t)dir * MTOT * 56;
    float* DELo = DEL2 + (size_t)dir * NM;

    const float4* XPf4 = reinterpret_cast<const float4*>(XP);
    size_t rowb[TM];
    #pragma unroll
    for (int r = 0; r < TM; ++r) {
        int s = s0 + r;
        int sE = dir ? (NS - 1 - s) : s;
        rowb[r] = ((size_t)(b * NS + sE)) * 96;
    }

    const float4* wcf4 = reinterpret_cast<const float4*>(wcP) + t;
    float acc[TM];
    #pragma unroll
    for (int r = 0; r < TM; ++r) acc[r] = b_c[t];
    float4 Wc = wcf4[0];
    float4 xc[TM];
    #pragma unroll
    for (int r = 0; r < TM; ++r) xc[r] = XPf4[rowb[r]];
    for (int i4 = 0; i4 < 96; ++i4) {
        int in_ = (i4 < 95) ? i4 + 1 : 95;
        float4 Wn = wcf4[(size_t)in_ * 384];
        float4 xn_[TM];
        #pragma unroll
        for (int r = 0; r < TM; ++r) xn_[r] = XPf4[rowb[r] + in_];
        #pragma unroll
        for (int e = 0; e < 4; ++e) {
            float wv = fget(Wc, e);
            #pragma unroll
            for (int r = 0; r < TM; ++r)
                acc[r] = fmaf(fget(xc[r], e), wv, acc[r]);
        }
        Wc = Wn;
        #pragma unroll
        for (int r = 0; r < TM; ++r) xc[r] = xn_[r];
    }

    #pragma unroll
    for (int r = 0; r < TM; ++r) {
        float s1 = acc[r], s2 = acc[r] * acc[r];
        #pragma unroll
        for (int o = 32; o; o >>= 1) {
            s1 += __shfl_xor(s1, o);
            s2 += __shfl_xor(s2, o);
        }
        if (lane == 0) { red[r][wid][0] = s1; red[r][wid][1] = s2; }
    }
    __syncthreads();
    float gt = g[t], btt = bt[t];
    #pragma unroll
    for (int r = 0; r < TM; ++r) {
        float s1 = 0.f, s2 = 0.f;
        #pragma unroll
        for (int w = 0; w < 6; ++w) { s1 += red[r][w][0]; s2 += red[r][w][1]; }
        float mu = s1 * (1.f / ND);
        float var = s2 * (1.f / ND) - mu * mu;
        float rs = rsqrtf(var + 1e-5f);
        float ln = (acc[r] - mu) * rs * gt + btt;
        uo[r][t] = ln;
        LNo[(size_t)(m0 + r) * ND + t] = ln;
    }
    __syncthreads();

    for (int r = wid; r < TM; r += 6) {
        if (lane < 56) {
            const float4* wdf4 = reinterpret_cast<const float4*>(wdbcP) + lane;
            const float4* uof4 = reinterpret_cast<const float4*>(&uo[r][0]);
            float a = 0.f;
            float4 Wd = wdf4[0];
            for (int i4 = 0; i4 < 96; ++i4) {
                int in_ = (i4 < 95) ? i4 + 1 : 95;
                float4 Wdn = wdf4[(size_t)in_ * 56];
                float4 uv = uof4[i4];
                a = fmaf(uv.x, Wd.x, a);
                a = fmaf(uv.y, Wd.y, a);
                a = fmaf(uv.z, Wd.z, a);
                a = fmaf(uv.w, Wd.w, a);
                Wd = Wdn;
            }
            dbcS[r][lane] = a;
            DBCo[(size_t)(m0 + r) * 56 + lane] = a;
        }
    }
    __syncthreads();

    float accD[TM]; float bd = b_dt[t];
    #pragma unroll
    for (int r = 0; r < TM; ++r) accD[r] = bd;
    for (int q = 0; q < 24; ++q) {
        float wv = wdtT[q * 384 + t];
        #pragma unroll
        for (int r = 0; r < TM; ++r) accD[r] = fmaf(dbcS[r][q], wv, accD[r]);
    }
    #pragma unroll
    for (int r = 0; r < TM; ++r) {
        float a = accD[r];
        DELo[(size_t)(m0 + r) * ND + t] =
            fmaxf(a, 0.f) + log1pf(__expf(-fabsf(a)));
    }
}

// ---------------- parallel scan ----------------
__global__ __launch_bounds__(384) void scan_s1(
    const float* __restrict__ DEL2, const float* __restrict__ LN2,
    const float* __restrict__ DBC2, const float* __restrict__ A_log1,
    const float* __restrict__ A_log2,
    float* __restrict__ P, float* __restrict__ H)
{
    __shared__ float bc[CHL][32];
    int blk = blockIdx.x;
    int c = blk & (NCH - 1);
    int db = blk >> 5;
    int dir = db >> 2, b = db & 3;
    int t = threadIdx.x;
    const float* del  = DEL2 + (size_t)dir * MTOT * ND;
    const float* u    = LN2  + (size_t)dir * MTOT * ND;
    const float* dbc  = DBC2 + (size_t)dir * MTOT * 56;
    const float* Alog = dir ? A_log2 : A_log1;

    for (int e = t; e < CHL * 32; e += 384) {
        int row = e >> 5, col = e & 31;
        bc[row][col] = dbc[((size_t)(b * NS + c * CHL + row)) * 56 + 24 + col];
    }
    __syncthreads();

    float A[NN], h[NN], p[NN];
    #pragma unroll
    for (int n = 0; n < NN; ++n) {
        A[n] = -__expf(Alog[(size_t)t * NN + n]);
        h[n] = 0.f; p[n] = 1.f;
    }
    for (int j = 0; j < CHL; ++j) {
        size_t rix = (size_t)b * NS + c * CHL + j;
        float dl = del[rix * ND + t];
        float uv = u[rix * ND + t];
        float dx = dl * uv;
        #pragma unroll
        for (int n = 0; n < NN; ++n) {
            float da = __expf(dl * A[n]);
            h[n] = fmaf(da, h[n], dx * bc[j][n]);
            p[n] *= da;
        }
    }
    size_t base = ((size_t)blk * ND + t) * NN;
    #pragma unroll
    for (int n = 0; n < NN; ++n) { P[base + n] = p[n]; H[base + n] = h[n]; }
}

__global__ __launch_bounds__(256) void scan_s2(
    float* __restrict__ P, const float* __restrict__ H)
{
    int gid = blockIdx.x * 256 + threadIdx.x;
    int n = gid & 15;
    int d = (gid >> 4) % ND;
    int db = gid / (16 * ND);
    float h = 0.f;
    for (int c = 0; c < NCH; ++c) {
        size_t idx = (((size_t)db * NCH + c) * ND + d) * NN + n;
        float p = P[idx];
        float hh = H[idx];
        P[idx] = h;
        h = fmaf(p, h, hh);
    }
}

__global__ __launch_bounds__(384) void scan_s3(
    const float* __restrict__ DEL2, const float* __restrict__ LN2,
    const float* __restrict__ DBC2, const float* __restrict__ A_log1,
    const float* __restrict__ A_log2, const float* __restrict__ D1,
    const float* __restrict__ D2, const float* __restrict__ Hinit,
    float* __restrict__ Y2)
{
    __shared__ float bc[CHL][32];
    int blk = blockIdx.x;
    int c = blk & (NCH - 1);
    int db = blk >> 5;
    int dir = db >> 2, b = db & 3;
    int t = threadIdx.x;
    const float* del  = DEL2 + (size_t)dir * MTOT * ND;
    const float* u    = LN2  + (size_t)dir * MTOT * ND;
    const float* dbc  = DBC2 + (size_t)dir * MTOT * 56;
    const float* Alog = dir ? A_log2 : A_log1;
    const float* Dv   = dir ? D2 : D1;
    float* y          = Y2 + (size_t)dir * MTOT * ND;

    for (int e = t; e < CHL * 32; e += 384) {
        int row = e >> 5, col = e & 31;
        bc[row][col] = dbc[((size_t)(b * NS + c * CHL + row)) * 56 + 24 + col];
    }
    __syncthreads();

    size_t base = ((size_t)blk * ND + t) * NN;
    float A[NN], h[NN];
    #pragma unroll
    for (int n = 0; n < NN; ++n) {
        A[n] = -__expf(Alog[(size_t)t * NN + n]);
        h[n] = Hinit[base + n];
    }
    float Dd = Dv[t];
    for (int j = 0; j < CHL; ++j) {
        size_t rix = (size_t)b * NS + c * CHL + j;
        float dl = del[rix * ND + t];
        float uv = u[rix * ND + t];
        float dx = dl * uv;
        float y0 = 0.f, y1 = 0.f;
        #pragma unroll
        for (int n = 0; n < NN; n += 2) {
            float da0 = __expf(dl * A[n]);
            float da1 = __expf(dl * A[n + 1]);
            h[n]     = fmaf(da0, h[n],     dx * bc[j][n]);
            h[n + 1] = fmaf(da1, h[n + 1], dx * bc[j][n + 1]);
            y0 = fmaf(h[n],     bc[j][16 + n],     y0);
            y1 = fmaf(h[n + 1], bc[j][16 + n + 1], y1);
        }
        y[rix * ND + t] = y0 + y1 + Dd * uv;
    }
}

// ---------------- gate: X3 = (YF+YB) * silu(Z1) ----------------
__global__ __launch_bounds__(256) void gate_k(
    const float* __restrict__ Z1, const float* __restrict__ YF,
    const float* __restrict__ YB, float* __restrict__ X3)
{
    int i = blockIdx.x * 256 + threadIdx.x;
    const float4* z4 = reinterpret_cast<const float4*>(Z1);
    const float4* f4 = reinterpret_cast<const float4*>(YF);
    const float4* b4 = reinterpret_cast<const float4*>(YB);
    float4* o4 = reinterpret_cast<float4*>(X3);
    float4 z = z4[i], f = f4[i], bb = b4[i], o;
    o.x = (f.x + bb.x) * (z.x / (1.f + __expf(-z.x)));
    o.y = (f.y + bb.y) * (z.y / (1.f + __expf(-z.y)));
    o.z = (f.z + bb.z) * (z.z / (1.f + __expf(-z.z)));
    o.w = (f.w + bb.w) * (z.w / (1.f + __expf(-z.w)));
    o4[i] = o;
}

// ---------------- final projection + skip ----------------
__global__ __launch_bounds__(384) void final_k(
    const float* __restrict__ x, const float* __restrict__ X3,
    const float* __restrict__ wp3P, const float* __restrict__ b_p3,
    float* __restrict__ out)
{
    int m0 = blockIdx.x * TMC;
    int t = threadIdx.x;
    const float4* x3f4 = reinterpret_cast<const float4*>(X3);
    const float4* wpf4 = reinterpret_cast<const float4*>(wp3P) + t;
    size_t rb = (size_t)m0 * 96;

    float acc[TMC]; float bp = b_p3[t];
    #pragma unroll
    for (int r = 0; r < TMC; ++r) acc[r] = bp;
    float4 Wp = wpf4[0];
    float4 xc[TMC];
    #pragma unroll
    for (int r = 0; r < TMC; ++r) xc[r] = x3f4[rb + (size_t)r * 96];
    for (int i4 = 0; i4 < 96; ++i4) {
        int in_ = (i4 < 95) ? i4 + 1 : 95;
        float4 Wn = wpf4[(size_t)in_ * 384];
        float4 xn_[TMC];
        #pragma unroll
        for (int r = 0; r < TMC; ++r) xn_[r] = x3f4[rb + (size_t)r * 96 + in_];
        #pragma unroll
        for (int e = 0; e < 4; ++e) {
            float wv = fget(Wp, e);
            #pragma unroll
            for (int r = 0; r < TMC; ++r)
                acc[r] = fmaf(fget(xc[r], e), wv, acc[r]);
        }
        Wp = Wn;
        #pragma unroll
        for (int r = 0; r < TMC; ++r) xc[r] = xn_[r];
    }
    #pragma unroll
    for (int r = 0; r < TMC; ++r) {
        size_t ix = (size_t)(m0 + r) * ND + t;
        out[ix] = acc[r] + x[ix];
    }
}

__global__ __launch_bounds__(256) void fill_f32(float* out, float v, int n)
{
    int i = blockIdx.x * 256 + threadIdx.x;
    if (i < n) out[i] = v;
}

// ---------------- launch ----------------
extern "C" void kernel_launch(void* const* d_in, const int* in_sizes, int n_in,
                              void* d_out, int out_size, void* d_ws, size_t ws_size,
                              hipStream_t stream) {
    float* out = (float*)d_out;

    if (out_size != MTOT * ND) {
        fill_f32<<<(out_size + 255) / 256, 256, 0, stream>>>(
            out, 70000.f + (float)(out_size >> 16), out_size);
        return;
    }

    const float* x      = (const float*)d_in[0];
    const float* w_p1   = (const float*)d_in[1];
    const float* b_p1   = (const float*)d_in[2];
    const float* w_p2   = (const float*)d_in[3];
    const float* b_p2   = (const float*)d_in[4];
    const float* w_p3   = (const float*)d_in[5];
    const float* b_p3   = (const float*)d_in[6];
    const float* w_cf   = (const float*)d_in[7];
    const float* b_cf   = (const float*)d_in[8];
    const float* w_cb   = (const float*)d_in[9];
    const float* b_cb   = (const float*)d_in[10];
    const float* g_n    = (const float*)d_in[11];
    const float* bt_n   = (const float*)d_in[12];
    const float* g_nf   = (const float*)d_in[13];
    const float* bt_nf  = (const float*)d_in[14];
    const float* g_nb   = (const float*)d_in[15];
    const float* bt_nb  = (const float*)d_in[16];
    const float* w_dbc1 = (const float*)d_in[17];
    const float* w_dt1  = (const float*)d_in[18];
    const float* b_dt1  = (const float*)d_in[19];
    const float* A_log1 = (const float*)d_in[20];
    const float* D1     = (const float*)d_in[21];
    const float* w_dbc2 = (const float*)d_in[22];
    const float* w_dt2  = (const float*)d_in[23];
    const float* b_dt2  = (const float*)d_in[24];
    const float* A_log2 = (const float*)d_in[25];
    const float* D2     = (const float*)d_in[26];

    const size_t NM = (size_t)MTOT * ND;
    const size_t N56 = (size_t)MTOT * 56;
    const size_t AGG = (size_t)2 * NB * NCH * ND * NN;
    size_t off = 0;
    float* ws = (float*)d_ws;
    float* XP    = ws + off; off += NM;
    float* Z1    = ws + off; off += NM;
    float* LN2   = ws + off; off += 2 * NM;
    float* DEL2  = ws + off; off += 2 * NM;
    float* Y2    = ws + off; off += 2 * NM;
    float* DBC2  = ws + off; off += 2 * N56;
    float* wp1P   = ws + off; off += 442368;
    float* wp2P   = ws + off; off += 442368;
    float* wp3P   = ws + off; off += 147456;
    float* wcfP   = ws + off; off += 147456;
    float* wcbP   = ws + off; off += 147456;
    float* wdbc1P = ws + off; off += 21504;
    float* wdbc2P = ws + off; off += 21504;
    float* wdt1T  = ws + off; off += 9216;
    float* wdt2T  = ws + off; off += 9216;
    float* Pagg  = ws + off; off += AGG;
    float* Hagg  = ws + off; off += AGG;
    const size_t ws_need = off;

    if (ws_size < ws_need * sizeof(float)) {
        fill_f32<<<(out_size + 255) / 256, 256, 0, stream>>>(out, 60000.f, out_size);
        return;
    }

    float* YF   = Y2;         float* YB   = Y2 + NM;
    // aliases (stream-ordered, lifetimes disjoint) — as round 10
    ushort_t* XH = (ushort_t*)Y2;
    ushort_t* XL = XH + (size_t)NB * NSP * ND;
    float* XNPf = DEL2;
    ushort_t* Wp = (ushort_t*)Hagg;
    int* flag1 = (int*)Pagg;          // V_A bad?
    int* flag2 = (int*)Pagg + 1;      // V_B also bad?
    int* galways = (int*)Pagg + 2;    // nonzero constant
    float* X3  = DEL2;

    prep_weights<<<15792, 256, 0, stream>>>(
        w_p1, w_p2, w_p3, w_cf, w_cb, w_dbc1, w_dbc2, w_dt1, w_dt2,
        Wp, wp1P, wp2P, wp3P, wcfP, wcbP, wdbc1P, wdbc2P, wdt1T, wdt2T);

    fill_f32<<<1, 256, 0, stream>>>((float*)Pagg, 0.f, 2);
    fill_f32<<<1, 256, 0, stream>>>((float*)Pagg + 2, 1.f, 1);

    ln1_k<<<MTOT / TM + 1, 384, 0, stream>>>(x, g_n, bt_n, XNPf, XH, XL);

    // V_A: A = contiguous-8, B = interleaved K=16 halves (tr-read-pinned B)
    conv_mfma<0, 1><<<64 * 12, 256, 0, stream>>>(
        galways, XH, XL, Wp, b_p2, b_p1, XP, Z1);
    verify_k<<<64, 384, 0, stream>>>(
        galways, XNPf, wp2P, b_p2, wp1P, b_p1, XP, Z1, flag1);

    // V_B: mirror (A = interleaved, B = contiguous-8), only if V_A failed
    conv_mfma<1, 0><<<64 * 12, 256, 0, stream>>>(
        flag1, XH, XL, Wp, b_p2, b_p1, XP, Z1);
    verify_k<<<64, 384, 0, stream>>>(
        flag1, XNPf, wp2P, b_p2, wp1P, b_p1, XP, Z1, flag2);

    // f32 fallback (only if both asymmetric combos failed)
    conv_fb<<<MTOT / TMC, 384, 0, stream>>>(
        flag2, XNPf, wp2P, b_p2, wp1P, b_p1, XP, Z1);

    dir2_k1<<<2 * (MTOT / TM), 384, 0, stream>>>(
        XP,
        wcfP, b_cf, g_nf, bt_nf, wdbc1P, wdt1T, b_dt1,
        wcbP, b_cb, g_nb, bt_nb, wdbc2P, wdt2T, b_dt2,
        LN2, DBC2, DEL2);

    scan_s1<<<2 * NB * NCH, 384, 0, stream>>>(
        DEL2, LN2, DBC2, A_log1, A_log2, Pagg, Hagg);
    scan_s2<<<(2 * NB * ND * NN) / 256, 256, 0, stream>>>(Pagg, Hagg);
    scan_s3<<<2 * NB * NCH, 384, 0, stream>>>(
        DEL2, LN2, DBC2, A_log1, A_log2, D1, D2, Pagg, Y2);

    gate_k<<<(int)(NM / 4 / 256), 256, 0, stream>>>(Z1, YF, YB, X3);

    final_k<<<MTOT / TMC, 384, 0, stream>>>(
        x, X3, wp3P, b_p3, out);
}